// Round 1
// 1205.125 us; speedup vs baseline: 1.0213x; 1.0213x over previous
//
#include <hip/hip_runtime.h>

#define DI __device__ __forceinline__

constexpr int Bb = 2, Ss = 4096, Hm = 2048, NHh = 16, HDd = 128;
constexpr int ROWS = Bb * Ss;   // 8192
constexpr int QKVN = 3 * Hm;    // 6144
constexpr int CC = 64;          // chunk length
constexpr int NC = Ss / CC;     // 64 chunks per (b,h)

typedef __bf16 bf16x8 __attribute__((ext_vector_type(8)));
typedef float f32x4 __attribute__((ext_vector_type(4)));

DI unsigned short f2bf(float f) {
  unsigned int u = __float_as_uint(f);
  u = u + 0x7FFFu + ((u >> 16) & 1u);   // round-to-nearest-even
  return (unsigned short)(u >> 16);
}
DI float bf2f(unsigned int u) { return __uint_as_float(u << 16); }
DI void ld_bf8(const unsigned short* p, float* f) {
  uint4 u = *(const uint4*)p;
  f[0] = bf2f(u.x & 0xffffu); f[1] = bf2f(u.x >> 16);
  f[2] = bf2f(u.y & 0xffffu); f[3] = bf2f(u.y >> 16);
  f[4] = bf2f(u.z & 0xffffu); f[5] = bf2f(u.z >> 16);
  f[6] = bf2f(u.w & 0xffffu); f[7] = bf2f(u.w >> 16);
}

// async global->LDS, 16B/lane, lds dest = base + lane*16 (wave-uniform base)
DI void gld16(const unsigned short* g, unsigned short* l) {
  __builtin_amdgcn_global_load_lds(
      (const __attribute__((address_space(1))) unsigned int*)g,
      (__attribute__((address_space(3))) unsigned int*)l, 16, 0, 0);
}

// ---------------- cast x -> bf16 ----------------
__global__ void cast_x_k(const float* __restrict__ x, unsigned short* __restrict__ xb) {
  int i = blockIdx.x * 256 + threadIdx.x;
  float4 f = ((const float4*)x)[i];
  ushort4 u;
  u.x = f2bf(f.x); u.y = f2bf(f.y); u.z = f2bf(f.z); u.w = f2bf(f.w);
  ((ushort4*)xb)[i] = u;
}

// ---------------- cast weights -> bf16 (Wq|Wk|Wv concat, Wo) ----------------
__global__ void cast_w_k(const float* __restrict__ Wq, const float* __restrict__ Wk,
                         const float* __restrict__ Wv, const float* __restrict__ Wo,
                         unsigned short* __restrict__ wqkv, unsigned short* __restrict__ wo) {
  const int W1 = Hm * Hm;
  int idx = blockIdx.x * 256 + threadIdx.x;
  for (int r = 0; r < 4; r++) {
    int i = idx + r * W1;
    if (i < W1)            wqkv[i] = f2bf(Wq[i]);
    else if (i < 2 * W1)   wqkv[i] = f2bf(Wk[i - W1]);
    else if (i < 3 * W1)   wqkv[i] = f2bf(Wv[i - 2 * W1]);
    else                   wo[i - 3 * W1] = f2bf(Wo[i - 3 * W1]);
  }
}

// ---------------- bf16 NT GEMM, m97-style global_load_lds staging ----------------
template <bool BF16_OUT>
__global__ __launch_bounds__(256) void gemm_bt(const unsigned short* __restrict__ A,
                                               const unsigned short* __restrict__ Bm,
                                               void* __restrict__ Cout,
                                               int M, int N, int Kd) {
  __shared__ __align__(16) unsigned short As[128 * 32];
  __shared__ __align__(16) unsigned short Bs[128 * 32];
  int tid = threadIdx.x;
  int bm = blockIdx.y * 128, bn = blockIdx.x * 128;
  int wave = tid >> 6, lane = tid & 63;
  int wm = (wave >> 1) * 64, wn = (wave & 1) * 64;
  int lm = lane & 15, lq = lane >> 4;
  f32x4 acc[4][4] = {};
  int sr = lane >> 2;        // 0..15 row within 16-row group
  int sc = (lane & 3) * 8;   // col in shorts

  for (int k0 = 0; k0 < Kd; k0 += 32) {
    __syncthreads();
#pragma unroll
    for (int i = 0; i < 2; i++) {
      int inst = (wave << 1) + i;          // 0..7, 16 rows each
      int r = inst * 16 + sr;
      gld16(&A[(size_t)(bm + r) * Kd + k0 + sc], &As[inst * 512]);
      gld16(&Bm[(size_t)(bn + r) * Kd + k0 + sc], &Bs[inst * 512]);
    }
    __syncthreads();
    bf16x8 af[4], bfr[4];
#pragma unroll
    for (int i = 0; i < 4; i++) af[i]  = *(const bf16x8*)&As[(wm + i * 16 + lm) * 32 + lq * 8];
#pragma unroll
    for (int j = 0; j < 4; j++) bfr[j] = *(const bf16x8*)&Bs[(wn + j * 16 + lm) * 32 + lq * 8];
#pragma unroll
    for (int i = 0; i < 4; i++)
#pragma unroll
      for (int j = 0; j < 4; j++)
        acc[i][j] = __builtin_amdgcn_mfma_f32_16x16x32_bf16(af[i], bfr[j], acc[i][j], 0, 0, 0);
  }
#pragma unroll
  for (int i = 0; i < 4; i++)
#pragma unroll
    for (int j = 0; j < 4; j++) {
      int row = bm + wm + i * 16 + lq * 4;
      int col = bn + wn + j * 16 + lm;
#pragma unroll
      for (int r = 0; r < 4; r++) {
        if (BF16_OUT)
          ((unsigned short*)Cout)[(size_t)(row + r) * N + col] = f2bf(acc[i][j][r]);
        else
          ((float*)Cout)[(size_t)(row + r) * N + col] = acc[i][j][r];
      }
    }
}

// ---------------- causal conv K=4 + silu + (l2norm for q/k), bf16 in/out ----------------
__global__ __launch_bounds__(256) void conv_k(const unsigned short* __restrict__ qkvh,
                                              const float* __restrict__ cwq,
                                              const float* __restrict__ cwk,
                                              const float* __restrict__ cwv,
                                              unsigned short* __restrict__ qb,
                                              unsigned short* __restrict__ kb,
                                              unsigned short* __restrict__ vb) {
  __shared__ __align__(16) float sm[32 * 260];   // pad 260: bank stride 4, not 0
  __shared__ float fac[64];
  int tid = threadIdx.x;
  int cblk = blockIdx.x * 256;
  int s0 = blockIdx.y * 32;
  int z = blockIdx.z;
  int sel = z >> 1, b = z & 1;
  const float* cw = sel == 0 ? cwq : (sel == 1 ? cwk : cwv);
  int c = cblk + tid;
  float4 w = ((const float4*)cw)[c];
  const unsigned short* in = qkvh + (size_t)b * Ss * QKVN + sel * Hm + c;
  float x0 = (s0 >= 3) ? bf2f(in[(size_t)(s0 - 3) * QKVN]) : 0.f;
  float x1 = (s0 >= 2) ? bf2f(in[(size_t)(s0 - 2) * QKVN]) : 0.f;
  float x2 = (s0 >= 1) ? bf2f(in[(size_t)(s0 - 1) * QKVN]) : 0.f;
  for (int si = 0; si < 32; si++) {
    float x3 = bf2f(in[(size_t)(s0 + si) * QKVN]);
    float a = w.x * x0 + w.y * x1 + w.z * x2 + w.w * x3;
    sm[si * 260 + tid] = a / (1.f + __expf(-a));
    x0 = x1; x1 = x2; x2 = x3;
  }
  __syncthreads();
  if (sel < 2) {
    int si = tid >> 3, p = tid & 7;
    const float* row = &sm[si * 260 + p * 32];
    float ss = 0.f;
#pragma unroll
    for (int j = 0; j < 32; j += 4) {
      float4 v4 = *(const float4*)(row + j);
      ss += v4.x * v4.x + v4.y * v4.y + v4.z * v4.z + v4.w * v4.w;
    }
    ss += __shfl_xor(ss, 1);
    ss += __shfl_xor(ss, 2);
    float f = rsqrtf(ss + 1e-6f);
    if (sel == 0) f *= 0.08838834764831845f;
    if ((p & 3) == 0) fac[si * 2 + (p >> 2)] = f;
  }
  __syncthreads();
  unsigned short* outp = sel == 0 ? qb : (sel == 1 ? kb : vb);
  int hl = tid >> 7;
  for (int si = 0; si < 32; si++) {
    float val = sm[si * 260 + tid];
    if (sel < 2) val *= fac[si * 2 + hl];
    outp[(size_t)(b * Ss + s0 + si) * Hm + cblk + tid] = f2bf(val);
  }
}

// ---------------- beta = sigmoid(x @ Wb^T), fp32 ----------------
__global__ __launch_bounds__(256) void beta_k(const float* __restrict__ x,
                                              const float* __restrict__ Wbm,
                                              float* __restrict__ beta) {
  int wid = threadIdx.x >> 6, lane = threadIdx.x & 63;
  int row = blockIdx.x * 4 + wid;
  int h = lane & 15, part = lane >> 4;
  const float* xr = x + (size_t)row * Hm + part * 512;
  const float* wr = Wbm + (size_t)h * Hm + part * 512;
  float acc = 0.f;
  for (int j = 0; j < 512; j += 4) {
    float4 xv = *(const float4*)(xr + j);
    float4 wv = *(const float4*)(wr + j);
    acc += xv.x * wv.x + xv.y * wv.y + xv.z * wv.z + xv.w * wv.w;
  }
  acc += __shfl_xor(acc, 16);
  acc += __shfl_xor(acc, 32);
  if (part == 0) beta[(size_t)row * NHh + h] = 1.f / (1.f + __expf(-acc));
}

// ---------------- recA: per-chunk WY precompute + At, doubling-based inverse ----------------
// grid (NC, 32). Outputs: W[cid][t][d], U[cid][t][v], Kt[cid][d][s]; At into kg's own chunk cols [0,64)
__global__ __launch_bounds__(256) void recA_k(const unsigned short* __restrict__ qg,
                                              unsigned short* kg,   // read K, write At
                                              const unsigned short* __restrict__ vg,
                                              const float* __restrict__ beta,
                                              unsigned short* __restrict__ Wo_,
                                              unsigned short* __restrict__ Uo,
                                              unsigned short* __restrict__ Kto) {
  __shared__ __align__(16) unsigned short Kc[64 * 136];
  __shared__ __align__(16) unsigned short Qc[64 * 136];
  __shared__ __align__(16) unsigned short Vt[128 * 72];
  __shared__ __align__(16) unsigned short Kt[128 * 72];
  __shared__ __align__(16) unsigned short Xa[64 * 72], Xat[64 * 72];
  __shared__ __align__(16) unsigned short Xb2[64 * 72], Xbt[64 * 72];
  __shared__ __align__(16) unsigned short Pa[64 * 72], Pb[64 * 72];
  __shared__ float bl[64];
  int tid = threadIdx.x;
  int c = blockIdx.x, bh = blockIdx.y;
  int b = bh >> 4, h = bh & 15;
  size_t cid = (size_t)bh * NC + c;
  size_t rowbase = (size_t)b * Ss + (size_t)c * CC;
  int wave = tid >> 6, lane = tid & 63, lm = lane & 15, lq = lane >> 4;

  // stage K, Q chunks (16B), V transposed (scalar), beta
  for (int idx = tid; idx < 1024; idx += 256) {
    int r = idx >> 4, c8 = (idx & 15) * 8;
    *(uint4*)&Kc[r * 136 + c8] = *(const uint4*)&kg[(rowbase + r) * Hm + h * HDd + c8];
    *(uint4*)&Qc[r * 136 + c8] = *(const uint4*)&qg[(rowbase + r) * Hm + h * HDd + c8];
  }
  for (int idx = tid; idx < 8192; idx += 256) {
    int s = idx >> 7, vv = idx & 127;
    Vt[vv * 72 + s] = vg[(rowbase + s) * Hm + h * HDd + vv];
  }
  if (tid < 64) bl[tid] = beta[(rowbase + tid) * NHh + h];
  __syncthreads();

  // Kt = K^T (LDS transpose)
  for (int idx = tid; idx < 8192; idx += 256) {
    int s = idx >> 7, d = idx & 127;
    Kt[d * 72 + s] = Kc[s * 136 + d];
  }
  // accA = K K^T -> M = -strict_tril(diag(beta) K K^T); write M, M^T, P0 = I + M
  {
    f32x4 accA[4] = {};
#pragma unroll
    for (int kk = 0; kk < 4; kk++) {
      bf16x8 af = *(const bf16x8*)&Kc[(wave * 16 + lm) * 136 + kk * 32 + lq * 8];
#pragma unroll
      for (int st = 0; st < 4; st++) {
        bf16x8 bfr = *(const bf16x8*)&Kc[(st * 16 + lm) * 136 + kk * 32 + lq * 8];
        accA[st] = __builtin_amdgcn_mfma_f32_16x16x32_bf16(af, bfr, accA[st], 0, 0, 0);
      }
    }
#pragma unroll
    for (int st = 0; st < 4; st++)
#pragma unroll
      for (int r = 0; r < 4; r++) {
        int t = wave * 16 + lq * 4 + r, s = st * 16 + lm;
        float m = (t > s) ? -bl[t] * accA[st][r] : 0.f;
        unsigned short mb = f2bf(m);
        Xa[t * 72 + s] = mb;
        Xat[s * 72 + t] = mb;
        Pa[t * 72 + s] = (t == s) ? f2bf(1.f) : mb;
      }
  }
  // At = mask(Q K^T) written into kg's own chunk region cols [0,64)
  {
    f32x4 accQ[4] = {};
#pragma unroll
    for (int kk = 0; kk < 4; kk++) {
      bf16x8 af = *(const bf16x8*)&Qc[(wave * 16 + lm) * 136 + kk * 32 + lq * 8];
#pragma unroll
      for (int st = 0; st < 4; st++) {
        bf16x8 bfr = *(const bf16x8*)&Kc[(st * 16 + lm) * 136 + kk * 32 + lq * 8];
        accQ[st] = __builtin_amdgcn_mfma_f32_16x16x32_bf16(af, bfr, accQ[st], 0, 0, 0);
      }
    }
#pragma unroll
    for (int st = 0; st < 4; st++)
#pragma unroll
      for (int r = 0; r < 4; r++) {
        int t = wave * 16 + lq * 4 + r, s = st * 16 + lm;
        kg[(rowbase + t) * Hm + h * HDd + s] = (s <= t) ? f2bf(accQ[st][r]) : (unsigned short)0;
      }
  }
  __syncthreads();

  // doubling: T = (I-M)^-1 = prod_{k=0..5} (I + M^(2^k)); carry (X, X^T) pairs
  unsigned short *X = Xa, *Xt = Xat, *Xn = Xb2, *Xnt = Xbt, *P = Pa, *Pn = Pb;
  for (int lvl = 1; lvl <= 5; lvl++) {
    // Xn = NT(X, Xt) = X*X ; Xnt = NT(Xt, X) = (X*X)^T
    f32x4 a1[4] = {}, a2[4] = {};
#pragma unroll
    for (int kk = 0; kk < 2; kk++) {
      bf16x8 afx  = *(const bf16x8*)&X[(wave * 16 + lm) * 72 + kk * 32 + lq * 8];
      bf16x8 afxt = *(const bf16x8*)&Xt[(wave * 16 + lm) * 72 + kk * 32 + lq * 8];
#pragma unroll
      for (int st = 0; st < 4; st++) {
        bf16x8 bx  = *(const bf16x8*)&X[(st * 16 + lm) * 72 + kk * 32 + lq * 8];
        bf16x8 bxt = *(const bf16x8*)&Xt[(st * 16 + lm) * 72 + kk * 32 + lq * 8];
        a1[st] = __builtin_amdgcn_mfma_f32_16x16x32_bf16(afx, bxt, a1[st], 0, 0, 0);
        a2[st] = __builtin_amdgcn_mfma_f32_16x16x32_bf16(afxt, bx, a2[st], 0, 0, 0);
      }
    }
#pragma unroll
    for (int st = 0; st < 4; st++)
#pragma unroll
      for (int r = 0; r < 4; r++) {
        int t = wave * 16 + lq * 4 + r, s = st * 16 + lm;
        Xn[t * 72 + s]  = f2bf(a1[st][r]);
        Xnt[t * 72 + s] = f2bf(a2[st][r]);
      }
    __syncthreads();
    // Pn = P + P*Xn = NT(P, Xnt) with acc seeded by P
    f32x4 ap[4];
#pragma unroll
    for (int st = 0; st < 4; st++)
#pragma unroll
      for (int r = 0; r < 4; r++)
        ap[st][r] = bf2f(P[(wave * 16 + lq * 4 + r) * 72 + st * 16 + lm]);
#pragma unroll
    for (int kk = 0; kk < 2; kk++) {
      bf16x8 afp = *(const bf16x8*)&P[(wave * 16 + lm) * 72 + kk * 32 + lq * 8];
#pragma unroll
      for (int st = 0; st < 4; st++) {
        bf16x8 bxnt = *(const bf16x8*)&Xnt[(st * 16 + lm) * 72 + kk * 32 + lq * 8];
        ap[st] = __builtin_amdgcn_mfma_f32_16x16x32_bf16(afp, bxnt, ap[st], 0, 0, 0);
      }
    }
#pragma unroll
    for (int st = 0; st < 4; st++)
#pragma unroll
      for (int r = 0; r < 4; r++) {
        int t = wave * 16 + lq * 4 + r, s = st * 16 + lm;
        // last level: fold in diag(beta) -> Tb
        Pn[t * 72 + s] = f2bf((lvl == 5) ? ap[st][r] * bl[s] : ap[st][r]);
      }
    // swap
    unsigned short* tmp;
    tmp = X; X = Xn; Xn = tmp;
    tmp = Xt; Xt = Xnt; Xnt = tmp;
    tmp = P; P = Pn; Pn = tmp;
    __syncthreads();
  }

  // store Kt to global
  for (int idx = tid; idx < 1024; idx += 256) {
    int d = idx >> 3, s8 = (idx & 7) * 8;
    *(uint4*)&Kto[cid * 8192 + d * 64 + s8] = *(const uint4*)&Kt[d * 72 + s8];
  }
  // U = NT(Tb, Vt) ; W = NT(Tb, Kt)   (Tb = P)
  {
    unsigned short* Up = Uo + cid * 8192;
    unsigned short* Wp = Wo_ + cid * 8192;
    f32x4 accU[8] = {}, accW[8] = {};
#pragma unroll
    for (int kk = 0; kk < 2; kk++) {
      bf16x8 af = *(const bf16x8*)&P[(wave * 16 + lm) * 72 + kk * 32 + lq * 8];
#pragma unroll
      for (int nt = 0; nt < 8; nt++) {
        bf16x8 bv = *(const bf16x8*)&Vt[(nt * 16 + lm) * 72 + kk * 32 + lq * 8];
        bf16x8 bk = *(const bf16x8*)&Kt[(nt * 16 + lm) * 72 + kk * 32 + lq * 8];
        accU[nt] = __builtin_amdgcn_mfma_f32_16x16x32_bf16(af, bv, accU[nt], 0, 0, 0);
        accW[nt] = __builtin_amdgcn_mfma_f32_16x16x32_bf16(af, bk, accW[nt], 0, 0, 0);
      }
    }
#pragma unroll
    for (int nt = 0; nt < 8; nt++)
#pragma unroll
      for (int r = 0; r < 4; r++) {
        int t = wave * 16 + lq * 4 + r, n = nt * 16 + lm;
        Up[t * 128 + n] = f2bf(accU[nt][r]);
        Wp[t * 128 + n] = f2bf(accW[nt][r]);
      }
  }
}

// ---------------- recB: sequential chunk scan, 256 WGs (8 v-slices x 32 bh) ----------------
__global__ __launch_bounds__(256) void recB_k(const unsigned short* __restrict__ qg,
                                              const unsigned short* __restrict__ atg,
                                              const unsigned short* __restrict__ Wg,
                                              const unsigned short* __restrict__ Ug,
                                              const unsigned short* __restrict__ Ktg,
                                              unsigned short* __restrict__ og) {
  __shared__ __align__(16) unsigned short Wc[64 * 136];
  __shared__ __align__(16) unsigned short Qc[64 * 136];
  __shared__ __align__(16) unsigned short Ktc[128 * 72];
  __shared__ __align__(16) unsigned short Atc[64 * 72];
  __shared__ __align__(16) unsigned short Uc[64 * 24];
  __shared__ __align__(16) unsigned short Dt[16 * 72];
  __shared__ __align__(16) unsigned short Stb[16 * 136];
  __shared__ float St32[16 * 132];
  int tid = threadIdx.x;
  // XCD-aware swizzle: dispatcher assigns XCD = linear_block_id % 8. The 8
  // v-slice blocks of one (b,h) read the SAME W/Kt/Q/At chunk stream; map them
  // all to the same id%8 so they share one XCD's L2 instead of re-fetching
  // from HBM on 8 different XCDs. Bijective: 256 blocks, 256 = 8*32.
  //   lin = vs_orig + 8*bh_orig ; xcd = lin&7 ; slot = lin>>3 (0..31)
  //   bh = xcd + 8*(slot>>3)  (4 heads per XCD) ; vs = slot&7
  int lin = blockIdx.x + (blockIdx.y << 3);
  int xcd = lin & 7, slot = lin >> 3;
  int vs = slot & 7;
  int bh = xcd + ((slot >> 3) << 3);
  int b = bh >> 4, h = bh & 15, v0 = vs * 16;
  int wave = tid >> 6, lane = tid & 63, lm = lane & 15, lq = lane >> 4;

  for (int i = tid; i < 16 * 132; i += 256) St32[i] = 0.f;
  for (int i = tid; i < 16 * 136; i += 256) Stb[i] = 0;

  // prologue: stage chunk 0 directly
  {
    size_t cid0 = (size_t)bh * NC;
    size_t rb0 = (size_t)b * Ss;
    const unsigned short* Wp = Wg + cid0 * 8192;
    const unsigned short* Ktp = Ktg + cid0 * 8192;
    const unsigned short* Up = Ug + cid0 * 8192 + v0;
#pragma unroll
    for (int j = 0; j < 4; j++) {
      int idx = tid + j * 256;
      int r = idx >> 4, c8 = (idx & 15) * 8;
      *(uint4*)&Wc[r * 136 + c8] = *(const uint4*)&Wp[r * 128 + c8];
      *(uint4*)&Qc[r * 136 + c8] = *(const uint4*)&qg[(rb0 + r) * Hm + h * HDd + c8];
      int r2 = idx >> 3, d8 = (idx & 7) * 8;
      *(uint4*)&Ktc[r2 * 72 + d8] = *(const uint4*)&Ktp[r2 * 64 + d8];
    }
#pragma unroll
    for (int j = 0; j < 2; j++) {
      int idx = tid + j * 256;
      int t = idx >> 3, s8 = (idx & 7) * 8;
      *(uint4*)&Atc[t * 72 + s8] = *(const uint4*)&atg[(rb0 + t) * Hm + h * HDd + s8];
    }
    if (tid < 128) {
      int t = tid >> 1, c8 = (tid & 1) * 8;
      *(uint4*)&Uc[t * 24 + c8] = *(const uint4*)&Up[t * 128 + c8];
    }
  }
  __syncthreads();

  for (int c = 0; c < NC; c++) {
    size_t rb = (size_t)b * Ss + (size_t)c * CC;
    // issue prefetch of chunk c+1 into registers (consumed in write-slot)
    int cn = (c + 1 < NC) ? c + 1 : c;
    size_t cidn = (size_t)bh * NC + cn;
    size_t rbn = (size_t)b * Ss + (size_t)cn * CC;
    const unsigned short* Wpn = Wg + cidn * 8192;
    const unsigned short* Ktpn = Ktg + cidn * 8192;
    const unsigned short* Upn = Ug + cidn * 8192 + v0;
    uint4 pw[4], pq[4], pk[4], pa[2], pu;
#pragma unroll
    for (int j = 0; j < 4; j++) {
      int idx = tid + j * 256;
      int r = idx >> 4, c8 = (idx & 15) * 8;
      pw[j] = *(const uint4*)&Wpn[r * 128 + c8];
      pq[j] = *(const uint4*)&qg[(rbn + r) * Hm + h * HDd + c8];
      int r2 = idx >> 3, d8 = (idx & 7) * 8;
      pk[j] = *(const uint4*)&Ktpn[r2 * 64 + d8];
    }
#pragma unroll
    for (int j = 0; j < 2; j++) {
      int idx = tid + j * 256;
      int t = idx >> 3, s8 = (idx & 7) * 8;
      pa[j] = *(const uint4*)&atg[(rbn + t) * Hm + h * HDd + s8];
    }
    if (tid < 128) {
      int t = tid >> 1, c8 = (tid & 1) * 8;
      pu = *(const uint4*)&Upn[t * 128 + c8];
    }

    // phase2: accD = NT(Wc, Stb) [64t x 16v]; Dt[v][t] = U - accD
    {
      f32x4 accD = {};
#pragma unroll
      for (int kk = 0; kk < 4; kk++) {
        bf16x8 af = *(const bf16x8*)&Wc[(wave * 16 + lm) * 136 + kk * 32 + lq * 8];
        bf16x8 bfr = *(const bf16x8*)&Stb[lm * 136 + kk * 32 + lq * 8];
        accD = __builtin_amdgcn_mfma_f32_16x16x32_bf16(af, bfr, accD, 0, 0, 0);
      }
#pragma unroll
      for (int r = 0; r < 4; r++) {
        int t = wave * 16 + lq * 4 + r;
        float dv = bf2f(Uc[t * 24 + lm]) - accD[r];
        Dt[lm * 72 + t] = f2bf(dv);
      }
    }
    __syncthreads();

    // phase3+4 fused: accO = NT(Qc,Stb) + NT(Atc,Dt); accP = NT(Dt,Ktc)
    f32x4 accO = {};
    f32x4 accP[2] = {};
    {
#pragma unroll
      for (int kk = 0; kk < 4; kk++) {
        bf16x8 af = *(const bf16x8*)&Qc[(wave * 16 + lm) * 136 + kk * 32 + lq * 8];
        bf16x8 bfr = *(const bf16x8*)&Stb[lm * 136 + kk * 32 + lq * 8];
        accO = __builtin_amdgcn_mfma_f32_16x16x32_bf16(af, bfr, accO, 0, 0, 0);
      }
#pragma unroll
      for (int kk = 0; kk < 2; kk++) {
        bf16x8 af = *(const bf16x8*)&Atc[(wave * 16 + lm) * 72 + kk * 32 + lq * 8];
        bf16x8 bfr = *(const bf16x8*)&Dt[lm * 72 + kk * 32 + lq * 8];
        accO = __builtin_amdgcn_mfma_f32_16x16x32_bf16(af, bfr, accO, 0, 0, 0);
        bf16x8 afd = *(const bf16x8*)&Dt[lm * 72 + kk * 32 + lq * 8];
#pragma unroll
        for (int j = 0; j < 2; j++) {
          int dt = wave * 2 + j;
          bf16x8 bk = *(const bf16x8*)&Ktc[(dt * 16 + lm) * 72 + kk * 32 + lq * 8];
          accP[j] = __builtin_amdgcn_mfma_f32_16x16x32_bf16(afd, bk, accP[j], 0, 0, 0);
        }
      }
    }
    __syncthreads();

    // write-slot: O -> global, state update, store prefetched chunk
#pragma unroll
    for (int r = 0; r < 4; r++) {
      int t = wave * 16 + lq * 4 + r;
      og[(rb + t) * Hm + h * HDd + v0 + lm] = f2bf(accO[r]);
    }
#pragma unroll
    for (int j = 0; j < 2; j++) {
      int dt = wave * 2 + j;
#pragma unroll
      for (int r = 0; r < 4; r++) {
        int vv = lq * 4 + r, d = dt * 16 + lm;
        float ns = St32[vv * 132 + d] + accP[j][r];
        St32[vv * 132 + d] = ns;
        Stb[vv * 136 + d] = f2bf(ns);
      }
    }
#pragma unroll
    for (int j = 0; j < 4; j++) {
      int idx = tid + j * 256;
      int r = idx >> 4, c8 = (idx & 15) * 8;
      *(uint4*)&Wc[r * 136 + c8] = pw[j];
      *(uint4*)&Qc[r * 136 + c8] = pq[j];
      int r2 = idx >> 3, d8 = (idx & 7) * 8;
      *(uint4*)&Ktc[r2 * 72 + d8] = pk[j];
    }
#pragma unroll
    for (int j = 0; j < 2; j++) {
      int idx = tid + j * 256;
      int t = idx >> 3, s8 = (idx & 7) * 8;
      *(uint4*)&Atc[t * 72 + s8] = pa[j];
    }
    if (tid < 128) {
      int t = tid >> 1, c8 = (tid & 1) * 8;
      *(uint4*)&Uc[t * 24 + c8] = pu;
    }
    __syncthreads();
  }
}

// ---------------- RMSNorm over head_dim + bf16 in/out ----------------
__global__ __launch_bounds__(256) void rmsn_k(const unsigned short* __restrict__ o,
                                              const float* __restrict__ rw,
                                              unsigned short* __restrict__ ob) {
  int tid = threadIdx.x;
  size_t rowoff = (size_t)blockIdx.x * Hm + tid * 8;
  float f[8];
  ld_bf8(o + rowoff, f);
  float ss = f[0]*f[0] + f[1]*f[1] + f[2]*f[2] + f[3]*f[3] +
             f[4]*f[4] + f[5]*f[5] + f[6]*f[6] + f[7]*f[7];
  ss += __shfl_xor(ss, 1); ss += __shfl_xor(ss, 2); ss += __shfl_xor(ss, 4); ss += __shfl_xor(ss, 8);
  float sc = rsqrtf(ss * (1.f / 128.f) + 1e-5f);
  int d = (tid & 15) * 8;
  float4 wa = *(const float4*)(rw + d);
  float4 wb = *(const float4*)(rw + d + 4);
  ushort4 u0, u1;
  u0.x = f2bf(f[0] * sc * wa.x); u0.y = f2bf(f[1] * sc * wa.y);
  u0.z = f2bf(f[2] * sc * wa.z); u0.w = f2bf(f[3] * sc * wa.w);
  u1.x = f2bf(f[4] * sc * wb.x); u1.y = f2bf(f[5] * sc * wb.y);
  u1.z = f2bf(f[6] * sc * wb.z); u1.w = f2bf(f[7] * sc * wb.w);
  ((ushort4*)ob)[rowoff / 4] = u0;
  ((ushort4*)ob)[rowoff / 4 + 1] = u1;
}

extern "C" void kernel_launch(void* const* d_in, const int* in_sizes, int n_in,
                              void* d_out, int out_size, void* d_ws, size_t ws_size,
                              hipStream_t stream) {
  const float* x  = (const float*)d_in[0];
  const float* Wq = (const float*)d_in[1];
  const float* Wk = (const float*)d_in[2];
  const float* Wv = (const float*)d_in[3];
  const float* Wb = (const float*)d_in[4];
  const float* Wo = (const float*)d_in[5];
  const float* cq = (const float*)d_in[6];
  const float* ck = (const float*)d_in[7];
  const float* cv = (const float*)d_in[8];
  const float* rw = (const float*)d_in[9];

  // d_out (64MB) as scratch: [0:32) xb then o; [32:64) vb. GEMM2 overwrites with fp32 out.
  unsigned short* xb  = (unsigned short*)d_out;
  unsigned short* vb  = (unsigned short*)d_out + (size_t)ROWS * Hm;
  unsigned short* o_b = (unsigned short*)d_out;
  float* out = (float*)d_out;

  // ws: 192.5 MB (proven footprint)
  char* ws = (char*)d_ws;
  size_t off = 0;
  auto alloc = [&](size_t bytes) {
    void* p = ws + off;
    off = (off + bytes + 255) & ~(size_t)255;
    return p;
  };
  unsigned short* wqkv = (unsigned short*)alloc((size_t)QKVN * Hm * 2);   // 24MB
  unsigned short* wob  = (unsigned short*)alloc((size_t)Hm * Hm * 2);     //  8MB
  unsigned short* qkvh = (unsigned short*)alloc((size_t)ROWS * QKVN * 2); // 96MB
  unsigned short* qb   = (unsigned short*)alloc((size_t)ROWS * Hm * 2);   // 32MB
  unsigned short* kb   = (unsigned short*)alloc((size_t)ROWS * Hm * 2);   // 32MB (K, then At in cols [0,64) per chunk)
  float* beta          = (float*)alloc((size_t)ROWS * NHh * 4);           // 0.5MB
  // After conv, qkvh dead: WY buffers alias it (3 x 32MB = 96MB exact)
  unsigned short* Wch = qkvh;                              // [2048][64][128]
  unsigned short* Uch = qkvh + (size_t)2048 * 8192;        // [2048][64][128]
  unsigned short* Kth = qkvh + (size_t)2 * 2048 * 8192;    // [2048][128][64]
  unsigned short* obb = qkvh;  // rmsn out, after recB (W region dead)

  cast_x_k<<<ROWS * Hm / 1024, 256, 0, stream>>>(x, xb);
  cast_w_k<<<Hm * Hm / 256, 256, 0, stream>>>(Wq, Wk, Wv, Wo, wqkv, wob);
  gemm_bt<true><<<dim3(QKVN / 128, ROWS / 128), 256, 0, stream>>>(xb, wqkv, qkvh, ROWS, QKVN, Hm);
  beta_k<<<ROWS / 4, 256, 0, stream>>>(x, Wb, beta);
  conv_k<<<dim3(Hm / 256, Ss / 32, Bb * 3), 256, 0, stream>>>(qkvh, cq, ck, cv, qb, kb, vb);
  recA_k<<<dim3(NC, 32), 256, 0, stream>>>(qb, kb, vb, beta, Wch, Uch, Kth);
  recB_k<<<dim3(8, 32), 256, 0, stream>>>(qb, kb, Wch, Uch, Kth, o_b);
  rmsn_k<<<ROWS, 256, 0, stream>>>(o_b, rw, obb);
  gemm_bt<false><<<dim3(Hm / 128, ROWS / 128), 256, 0, stream>>>(obb, wob, out, ROWS, Hm, Hm);
}

// Round 2
// 1020.342 us; speedup vs baseline: 1.2063x; 1.1811x over previous
//
#include <hip/hip_runtime.h>

#define DI __device__ __forceinline__

constexpr int Bb = 2, Ss = 4096, Hm = 2048, NHh = 16, HDd = 128;
constexpr int ROWS = Bb * Ss;   // 8192
constexpr int QKVN = 3 * Hm;    // 6144
constexpr int CC = 64;          // chunk length
constexpr int NC = Ss / CC;     // 64 chunks per (b,h)

typedef __bf16 bf16x8 __attribute__((ext_vector_type(8)));
typedef float f32x4 __attribute__((ext_vector_type(4)));

DI unsigned short f2bf(float f) {
  unsigned int u = __float_as_uint(f);
  u = u + 0x7FFFu + ((u >> 16) & 1u);   // round-to-nearest-even
  return (unsigned short)(u >> 16);
}
DI float bf2f(unsigned int u) { return __uint_as_float(u << 16); }
DI void ld_bf8(const unsigned short* p, float* f) {
  uint4 u = *(const uint4*)p;
  f[0] = bf2f(u.x & 0xffffu); f[1] = bf2f(u.x >> 16);
  f[2] = bf2f(u.y & 0xffffu); f[3] = bf2f(u.y >> 16);
  f[4] = bf2f(u.z & 0xffffu); f[5] = bf2f(u.z >> 16);
  f[6] = bf2f(u.w & 0xffffu); f[7] = bf2f(u.w >> 16);
}

// async global->LDS, 16B/lane, lds dest = base + lane*16 (wave-uniform base)
DI void gld16(const unsigned short* g, unsigned short* l) {
  __builtin_amdgcn_global_load_lds(
      (const __attribute__((address_space(1))) unsigned int*)g,
      (__attribute__((address_space(3))) unsigned int*)l, 16, 0, 0);
}

// raw barrier with LDS-only drain: does NOT wait vmcnt (global loads/stores
// stay in flight across the barrier — T4 counted-vmcnt discipline).
DI void bar_lds() {
  asm volatile("s_waitcnt lgkmcnt(0)" ::: "memory");
  __builtin_amdgcn_s_barrier();
}

// ---------------- cast x -> bf16 ----------------
__global__ void cast_x_k(const float* __restrict__ x, unsigned short* __restrict__ xb) {
  int i = blockIdx.x * 256 + threadIdx.x;
  float4 f = ((const float4*)x)[i];
  ushort4 u;
  u.x = f2bf(f.x); u.y = f2bf(f.y); u.z = f2bf(f.z); u.w = f2bf(f.w);
  ((ushort4*)xb)[i] = u;
}

// ---------------- cast weights -> bf16 (Wq|Wk|Wv concat, Wo) ----------------
__global__ void cast_w_k(const float* __restrict__ Wq, const float* __restrict__ Wk,
                         const float* __restrict__ Wv, const float* __restrict__ Wo,
                         unsigned short* __restrict__ wqkv, unsigned short* __restrict__ wo) {
  const int W1 = Hm * Hm;
  int idx = blockIdx.x * 256 + threadIdx.x;
  for (int r = 0; r < 4; r++) {
    int i = idx + r * W1;
    if (i < W1)            wqkv[i] = f2bf(Wq[i]);
    else if (i < 2 * W1)   wqkv[i] = f2bf(Wk[i - W1]);
    else if (i < 3 * W1)   wqkv[i] = f2bf(Wv[i - 2 * W1]);
    else                   wo[i - 3 * W1] = f2bf(Wo[i - 3 * W1]);
  }
}

// ---------------- bf16 NT GEMM, m97-style global_load_lds staging ----------------
template <bool BF16_OUT>
__global__ __launch_bounds__(256) void gemm_bt(const unsigned short* __restrict__ A,
                                               const unsigned short* __restrict__ Bm,
                                               void* __restrict__ Cout,
                                               int M, int N, int Kd) {
  __shared__ __align__(16) unsigned short As[128 * 32];
  __shared__ __align__(16) unsigned short Bs[128 * 32];
  int tid = threadIdx.x;
  int bm = blockIdx.y * 128, bn = blockIdx.x * 128;
  int wave = tid >> 6, lane = tid & 63;
  int wm = (wave >> 1) * 64, wn = (wave & 1) * 64;
  int lm = lane & 15, lq = lane >> 4;
  f32x4 acc[4][4] = {};
  int sr = lane >> 2;        // 0..15 row within 16-row group
  int sc = (lane & 3) * 8;   // col in shorts

  for (int k0 = 0; k0 < Kd; k0 += 32) {
    __syncthreads();
#pragma unroll
    for (int i = 0; i < 2; i++) {
      int inst = (wave << 1) + i;          // 0..7, 16 rows each
      int r = inst * 16 + sr;
      gld16(&A[(size_t)(bm + r) * Kd + k0 + sc], &As[inst * 512]);
      gld16(&Bm[(size_t)(bn + r) * Kd + k0 + sc], &Bs[inst * 512]);
    }
    __syncthreads();
    bf16x8 af[4], bfr[4];
#pragma unroll
    for (int i = 0; i < 4; i++) af[i]  = *(const bf16x8*)&As[(wm + i * 16 + lm) * 32 + lq * 8];
#pragma unroll
    for (int j = 0; j < 4; j++) bfr[j] = *(const bf16x8*)&Bs[(wn + j * 16 + lm) * 32 + lq * 8];
#pragma unroll
    for (int i = 0; i < 4; i++)
#pragma unroll
      for (int j = 0; j < 4; j++)
        acc[i][j] = __builtin_amdgcn_mfma_f32_16x16x32_bf16(af[i], bfr[j], acc[i][j], 0, 0, 0);
  }
#pragma unroll
  for (int i = 0; i < 4; i++)
#pragma unroll
    for (int j = 0; j < 4; j++) {
      int row = bm + wm + i * 16 + lq * 4;
      int col = bn + wn + j * 16 + lm;
#pragma unroll
      for (int r = 0; r < 4; r++) {
        if (BF16_OUT)
          ((unsigned short*)Cout)[(size_t)(row + r) * N + col] = f2bf(acc[i][j][r]);
        else
          ((float*)Cout)[(size_t)(row + r) * N + col] = acc[i][j][r];
      }
    }
}

// ---------------- causal conv K=4 + silu + (l2norm for q/k), bf16 in/out ----------------
__global__ __launch_bounds__(256) void conv_k(const unsigned short* __restrict__ qkvh,
                                              const float* __restrict__ cwq,
                                              const float* __restrict__ cwk,
                                              const float* __restrict__ cwv,
                                              unsigned short* __restrict__ qb,
                                              unsigned short* __restrict__ kb,
                                              unsigned short* __restrict__ vb) {
  __shared__ __align__(16) float sm[32 * 260];   // pad 260: bank stride 4, not 0
  __shared__ float fac[64];
  int tid = threadIdx.x;
  int cblk = blockIdx.x * 256;
  int s0 = blockIdx.y * 32;
  int z = blockIdx.z;
  int sel = z >> 1, b = z & 1;
  const float* cw = sel == 0 ? cwq : (sel == 1 ? cwk : cwv);
  int c = cblk + tid;
  float4 w = ((const float4*)cw)[c];
  const unsigned short* in = qkvh + (size_t)b * Ss * QKVN + sel * Hm + c;
  float x0 = (s0 >= 3) ? bf2f(in[(size_t)(s0 - 3) * QKVN]) : 0.f;
  float x1 = (s0 >= 2) ? bf2f(in[(size_t)(s0 - 2) * QKVN]) : 0.f;
  float x2 = (s0 >= 1) ? bf2f(in[(size_t)(s0 - 1) * QKVN]) : 0.f;
  for (int si = 0; si < 32; si++) {
    float x3 = bf2f(in[(size_t)(s0 + si) * QKVN]);
    float a = w.x * x0 + w.y * x1 + w.z * x2 + w.w * x3;
    sm[si * 260 + tid] = a / (1.f + __expf(-a));
    x0 = x1; x1 = x2; x2 = x3;
  }
  __syncthreads();
  if (sel < 2) {
    int si = tid >> 3, p = tid & 7;
    const float* row = &sm[si * 260 + p * 32];
    float ss = 0.f;
#pragma unroll
    for (int j = 0; j < 32; j += 4) {
      float4 v4 = *(const float4*)(row + j);
      ss += v4.x * v4.x + v4.y * v4.y + v4.z * v4.z + v4.w * v4.w;
    }
    ss += __shfl_xor(ss, 1);
    ss += __shfl_xor(ss, 2);
    float f = rsqrtf(ss + 1e-6f);
    if (sel == 0) f *= 0.08838834764831845f;
    if ((p & 3) == 0) fac[si * 2 + (p >> 2)] = f;
  }
  __syncthreads();
  unsigned short* outp = sel == 0 ? qb : (sel == 1 ? kb : vb);
  int hl = tid >> 7;
  for (int si = 0; si < 32; si++) {
    float val = sm[si * 260 + tid];
    if (sel < 2) val *= fac[si * 2 + hl];
    outp[(size_t)(b * Ss + s0 + si) * Hm + cblk + tid] = f2bf(val);
  }
}

// ---------------- beta = sigmoid(x @ Wb^T), fp32 ----------------
__global__ __launch_bounds__(256) void beta_k(const float* __restrict__ x,
                                              const float* __restrict__ Wbm,
                                              float* __restrict__ beta) {
  int wid = threadIdx.x >> 6, lane = threadIdx.x & 63;
  int row = blockIdx.x * 4 + wid;
  int h = lane & 15, part = lane >> 4;
  const float* xr = x + (size_t)row * Hm + part * 512;
  const float* wr = Wbm + (size_t)h * Hm + part * 512;
  float acc = 0.f;
  for (int j = 0; j < 512; j += 4) {
    float4 xv = *(const float4*)(xr + j);
    float4 wv = *(const float4*)(wr + j);
    acc += xv.x * wv.x + xv.y * wv.y + xv.z * wv.z + xv.w * wv.w;
  }
  acc += __shfl_xor(acc, 16);
  acc += __shfl_xor(acc, 32);
  if (part == 0) beta[(size_t)row * NHh + h] = 1.f / (1.f + __expf(-acc));
}

// ---------------- recA: per-chunk WY precompute + At, doubling-based inverse ----------------
// grid (NC, 32). Outputs: W[cid][t][d], U[cid][t][v], Kt[cid][d][s]; At into kg's own chunk cols [0,64)
__global__ __launch_bounds__(256) void recA_k(const unsigned short* __restrict__ qg,
                                              unsigned short* kg,   // read K, write At
                                              const unsigned short* __restrict__ vg,
                                              const float* __restrict__ beta,
                                              unsigned short* __restrict__ Wo_,
                                              unsigned short* __restrict__ Uo,
                                              unsigned short* __restrict__ Kto) {
  __shared__ __align__(16) unsigned short Kc[64 * 136];
  __shared__ __align__(16) unsigned short Qc[64 * 136];
  __shared__ __align__(16) unsigned short Vt[128 * 72];
  __shared__ __align__(16) unsigned short Kt[128 * 72];
  __shared__ __align__(16) unsigned short Xa[64 * 72], Xat[64 * 72];
  __shared__ __align__(16) unsigned short Xb2[64 * 72], Xbt[64 * 72];
  __shared__ __align__(16) unsigned short Pa[64 * 72], Pb[64 * 72];
  __shared__ float bl[64];
  int tid = threadIdx.x;
  int c = blockIdx.x, bh = blockIdx.y;
  int b = bh >> 4, h = bh & 15;
  size_t cid = (size_t)bh * NC + c;
  size_t rowbase = (size_t)b * Ss + (size_t)c * CC;
  int wave = tid >> 6, lane = tid & 63, lm = lane & 15, lq = lane >> 4;

  // stage K, Q chunks (16B), V transposed (scalar), beta
  for (int idx = tid; idx < 1024; idx += 256) {
    int r = idx >> 4, c8 = (idx & 15) * 8;
    *(uint4*)&Kc[r * 136 + c8] = *(const uint4*)&kg[(rowbase + r) * Hm + h * HDd + c8];
    *(uint4*)&Qc[r * 136 + c8] = *(const uint4*)&qg[(rowbase + r) * Hm + h * HDd + c8];
  }
  for (int idx = tid; idx < 8192; idx += 256) {
    int s = idx >> 7, vv = idx & 127;
    Vt[vv * 72 + s] = vg[(rowbase + s) * Hm + h * HDd + vv];
  }
  if (tid < 64) bl[tid] = beta[(rowbase + tid) * NHh + h];
  __syncthreads();

  // Kt = K^T (LDS transpose)
  for (int idx = tid; idx < 8192; idx += 256) {
    int s = idx >> 7, d = idx & 127;
    Kt[d * 72 + s] = Kc[s * 136 + d];
  }
  // accA = K K^T -> M = -strict_tril(diag(beta) K K^T); write M, M^T, P0 = I + M
  {
    f32x4 accA[4] = {};
#pragma unroll
    for (int kk = 0; kk < 4; kk++) {
      bf16x8 af = *(const bf16x8*)&Kc[(wave * 16 + lm) * 136 + kk * 32 + lq * 8];
#pragma unroll
      for (int st = 0; st < 4; st++) {
        bf16x8 bfr = *(const bf16x8*)&Kc[(st * 16 + lm) * 136 + kk * 32 + lq * 8];
        accA[st] = __builtin_amdgcn_mfma_f32_16x16x32_bf16(af, bfr, accA[st], 0, 0, 0);
      }
    }
#pragma unroll
    for (int st = 0; st < 4; st++)
#pragma unroll
      for (int r = 0; r < 4; r++) {
        int t = wave * 16 + lq * 4 + r, s = st * 16 + lm;
        float m = (t > s) ? -bl[t] * accA[st][r] : 0.f;
        unsigned short mb = f2bf(m);
        Xa[t * 72 + s] = mb;
        Xat[s * 72 + t] = mb;
        Pa[t * 72 + s] = (t == s) ? f2bf(1.f) : mb;
      }
  }
  // At = mask(Q K^T) written into kg's own chunk region cols [0,64)
  {
    f32x4 accQ[4] = {};
#pragma unroll
    for (int kk = 0; kk < 4; kk++) {
      bf16x8 af = *(const bf16x8*)&Qc[(wave * 16 + lm) * 136 + kk * 32 + lq * 8];
#pragma unroll
      for (int st = 0; st < 4; st++) {
        bf16x8 bfr = *(const bf16x8*)&Kc[(st * 16 + lm) * 136 + kk * 32 + lq * 8];
        accQ[st] = __builtin_amdgcn_mfma_f32_16x16x32_bf16(af, bfr, accQ[st], 0, 0, 0);
      }
    }
#pragma unroll
    for (int st = 0; st < 4; st++)
#pragma unroll
      for (int r = 0; r < 4; r++) {
        int t = wave * 16 + lq * 4 + r, s = st * 16 + lm;
        kg[(rowbase + t) * Hm + h * HDd + s] = (s <= t) ? f2bf(accQ[st][r]) : (unsigned short)0;
      }
  }
  __syncthreads();

  // doubling: T = (I-M)^-1 = prod_{k=0..5} (I + M^(2^k)); carry (X, X^T) pairs
  unsigned short *X = Xa, *Xt = Xat, *Xn = Xb2, *Xnt = Xbt, *P = Pa, *Pn = Pb;
  for (int lvl = 1; lvl <= 5; lvl++) {
    // Xn = NT(X, Xt) = X*X ; Xnt = NT(Xt, X) = (X*X)^T
    f32x4 a1[4] = {}, a2[4] = {};
#pragma unroll
    for (int kk = 0; kk < 2; kk++) {
      bf16x8 afx  = *(const bf16x8*)&X[(wave * 16 + lm) * 72 + kk * 32 + lq * 8];
      bf16x8 afxt = *(const bf16x8*)&Xt[(wave * 16 + lm) * 72 + kk * 32 + lq * 8];
#pragma unroll
      for (int st = 0; st < 4; st++) {
        bf16x8 bx  = *(const bf16x8*)&X[(st * 16 + lm) * 72 + kk * 32 + lq * 8];
        bf16x8 bxt = *(const bf16x8*)&Xt[(st * 16 + lm) * 72 + kk * 32 + lq * 8];
        a1[st] = __builtin_amdgcn_mfma_f32_16x16x32_bf16(afx, bxt, a1[st], 0, 0, 0);
        a2[st] = __builtin_amdgcn_mfma_f32_16x16x32_bf16(afxt, bx, a2[st], 0, 0, 0);
      }
    }
#pragma unroll
    for (int st = 0; st < 4; st++)
#pragma unroll
      for (int r = 0; r < 4; r++) {
        int t = wave * 16 + lq * 4 + r, s = st * 16 + lm;
        Xn[t * 72 + s]  = f2bf(a1[st][r]);
        Xnt[t * 72 + s] = f2bf(a2[st][r]);
      }
    __syncthreads();
    // Pn = P + P*Xn = NT(P, Xnt) with acc seeded by P
    f32x4 ap[4];
#pragma unroll
    for (int st = 0; st < 4; st++)
#pragma unroll
      for (int r = 0; r < 4; r++)
        ap[st][r] = bf2f(P[(wave * 16 + lq * 4 + r) * 72 + st * 16 + lm]);
#pragma unroll
    for (int kk = 0; kk < 2; kk++) {
      bf16x8 afp = *(const bf16x8*)&P[(wave * 16 + lm) * 72 + kk * 32 + lq * 8];
#pragma unroll
      for (int st = 0; st < 4; st++) {
        bf16x8 bxnt = *(const bf16x8*)&Xnt[(st * 16 + lm) * 72 + kk * 32 + lq * 8];
        ap[st] = __builtin_amdgcn_mfma_f32_16x16x32_bf16(afp, bxnt, ap[st], 0, 0, 0);
      }
    }
#pragma unroll
    for (int st = 0; st < 4; st++)
#pragma unroll
      for (int r = 0; r < 4; r++) {
        int t = wave * 16 + lq * 4 + r, s = st * 16 + lm;
        // last level: fold in diag(beta) -> Tb
        Pn[t * 72 + s] = f2bf((lvl == 5) ? ap[st][r] * bl[s] : ap[st][r]);
      }
    // swap
    unsigned short* tmp;
    tmp = X; X = Xn; Xn = tmp;
    tmp = Xt; Xt = Xnt; Xnt = tmp;
    tmp = P; P = Pn; Pn = tmp;
    __syncthreads();
  }

  // store Kt to global
  for (int idx = tid; idx < 1024; idx += 256) {
    int d = idx >> 3, s8 = (idx & 7) * 8;
    *(uint4*)&Kto[cid * 8192 + d * 64 + s8] = *(const uint4*)&Kt[d * 72 + s8];
  }
  // U = NT(Tb, Vt) ; W = NT(Tb, Kt)   (Tb = P)
  {
    unsigned short* Up = Uo + cid * 8192;
    unsigned short* Wp = Wo_ + cid * 8192;
    f32x4 accU[8] = {}, accW[8] = {};
#pragma unroll
    for (int kk = 0; kk < 2; kk++) {
      bf16x8 af = *(const bf16x8*)&P[(wave * 16 + lm) * 72 + kk * 32 + lq * 8];
#pragma unroll
      for (int nt = 0; nt < 8; nt++) {
        bf16x8 bv = *(const bf16x8*)&Vt[(nt * 16 + lm) * 72 + kk * 32 + lq * 8];
        bf16x8 bk = *(const bf16x8*)&Kt[(nt * 16 + lm) * 72 + kk * 32 + lq * 8];
        accU[nt] = __builtin_amdgcn_mfma_f32_16x16x32_bf16(af, bv, accU[nt], 0, 0, 0);
        accW[nt] = __builtin_amdgcn_mfma_f32_16x16x32_bf16(af, bk, accW[nt], 0, 0, 0);
      }
    }
#pragma unroll
    for (int nt = 0; nt < 8; nt++)
#pragma unroll
      for (int r = 0; r < 4; r++) {
        int t = wave * 16 + lq * 4 + r, n = nt * 16 + lm;
        Up[t * 128 + n] = f2bf(accU[nt][r]);
        Wp[t * 128 + n] = f2bf(accW[nt][r]);
      }
  }
}

// ---------------- recB: sequential chunk scan, 256 WGs (8 v-slices x 32 bh) ----------------
__global__ __launch_bounds__(256) void recB_k(const unsigned short* __restrict__ qg,
                                              const unsigned short* __restrict__ atg,
                                              const unsigned short* __restrict__ Wg,
                                              const unsigned short* __restrict__ Ug,
                                              const unsigned short* __restrict__ Ktg,
                                              unsigned short* __restrict__ og) {
  __shared__ __align__(16) unsigned short Wc[64 * 136];
  __shared__ __align__(16) unsigned short Qc[64 * 136];
  __shared__ __align__(16) unsigned short Ktc[128 * 72];
  __shared__ __align__(16) unsigned short Atc[64 * 72];
  __shared__ __align__(16) unsigned short Uc[64 * 24];
  __shared__ __align__(16) unsigned short Dt[16 * 72];
  __shared__ __align__(16) unsigned short Stb[16 * 136];
  __shared__ float St32[16 * 132];
  int tid = threadIdx.x;
  // XCD-aware swizzle: all 8 v-slices of one (b,h) on the same XCD (id%8).
  int lin = blockIdx.x + (blockIdx.y << 3);
  int xcd = lin & 7, slot = lin >> 3;
  int vs = slot & 7;
  int bh = xcd + ((slot >> 3) << 3);
  int b = bh >> 4, h = bh & 15, v0 = vs * 16;
  int wave = tid >> 6, lane = tid & 63, lm = lane & 15, lq = lane >> 4;

  for (int i = tid; i < 16 * 132; i += 256) St32[i] = 0.f;
  for (int i = tid; i < 16 * 136; i += 256) Stb[i] = 0;

  // prologue: stage chunk 0 directly
  {
    size_t cid0 = (size_t)bh * NC;
    size_t rb0 = (size_t)b * Ss;
    const unsigned short* Wp = Wg + cid0 * 8192;
    const unsigned short* Ktp = Ktg + cid0 * 8192;
    const unsigned short* Up = Ug + cid0 * 8192 + v0;
#pragma unroll
    for (int j = 0; j < 4; j++) {
      int idx = tid + j * 256;
      int r = idx >> 4, c8 = (idx & 15) * 8;
      *(uint4*)&Wc[r * 136 + c8] = *(const uint4*)&Wp[r * 128 + c8];
      *(uint4*)&Qc[r * 136 + c8] = *(const uint4*)&qg[(rb0 + r) * Hm + h * HDd + c8];
      int r2 = idx >> 3, d8 = (idx & 7) * 8;
      *(uint4*)&Ktc[r2 * 72 + d8] = *(const uint4*)&Ktp[r2 * 64 + d8];
    }
#pragma unroll
    for (int j = 0; j < 2; j++) {
      int idx = tid + j * 256;
      int t = idx >> 3, s8 = (idx & 7) * 8;
      *(uint4*)&Atc[t * 72 + s8] = *(const uint4*)&atg[(rb0 + t) * Hm + h * HDd + s8];
    }
    if (tid < 128) {
      int t = tid >> 1, c8 = (tid & 1) * 8;
      *(uint4*)&Uc[t * 24 + c8] = *(const uint4*)&Up[t * 128 + c8];
    }
  }
  __syncthreads();

  for (int c = 0; c < NC; c++) {
    size_t rb = (size_t)b * Ss + (size_t)c * CC;
    // issue prefetch of chunk c+1 into registers (consumed in write-slot).
    // With bar_lds() these loads stay in flight across BOTH phase barriers;
    // the only wait is the compiler's counted vmcnt at first register use.
    int cn = (c + 1 < NC) ? c + 1 : c;
    size_t cidn = (size_t)bh * NC + cn;
    size_t rbn = (size_t)b * Ss + (size_t)cn * CC;
    const unsigned short* Wpn = Wg + cidn * 8192;
    const unsigned short* Ktpn = Ktg + cidn * 8192;
    const unsigned short* Upn = Ug + cidn * 8192 + v0;
    uint4 pw[4], pq[4], pk[4], pa[2], pu;
#pragma unroll
    for (int j = 0; j < 4; j++) {
      int idx = tid + j * 256;
      int r = idx >> 4, c8 = (idx & 15) * 8;
      pw[j] = *(const uint4*)&Wpn[r * 128 + c8];
      pq[j] = *(const uint4*)&qg[(rbn + r) * Hm + h * HDd + c8];
      int r2 = idx >> 3, d8 = (idx & 7) * 8;
      pk[j] = *(const uint4*)&Ktpn[r2 * 64 + d8];
    }
#pragma unroll
    for (int j = 0; j < 2; j++) {
      int idx = tid + j * 256;
      int t = idx >> 3, s8 = (idx & 7) * 8;
      pa[j] = *(const uint4*)&atg[(rbn + t) * Hm + h * HDd + s8];
    }
    if (tid < 128) {
      int t = tid >> 1, c8 = (tid & 1) * 8;
      pu = *(const uint4*)&Upn[t * 128 + c8];
    }

    // phase2: accD = NT(Wc, Stb) [64t x 16v]; Dt[v][t] = U - accD
    {
      f32x4 accD = {};
#pragma unroll
      for (int kk = 0; kk < 4; kk++) {
        bf16x8 af = *(const bf16x8*)&Wc[(wave * 16 + lm) * 136 + kk * 32 + lq * 8];
        bf16x8 bfr = *(const bf16x8*)&Stb[lm * 136 + kk * 32 + lq * 8];
        accD = __builtin_amdgcn_mfma_f32_16x16x32_bf16(af, bfr, accD, 0, 0, 0);
      }
#pragma unroll
      for (int r = 0; r < 4; r++) {
        int t = wave * 16 + lq * 4 + r;
        float dv = bf2f(Uc[t * 24 + lm]) - accD[r];
        Dt[lm * 72 + t] = f2bf(dv);
      }
    }
    bar_lds();   // A: Dt visible; prefetch loads remain in flight

    // phase3+4 fused: accO = NT(Qc,Stb) + NT(Atc,Dt); accP = NT(Dt,Ktc)
    f32x4 accO = {};
    f32x4 accP[2] = {};
    {
#pragma unroll
      for (int kk = 0; kk < 4; kk++) {
        bf16x8 af = *(const bf16x8*)&Qc[(wave * 16 + lm) * 136 + kk * 32 + lq * 8];
        bf16x8 bfr = *(const bf16x8*)&Stb[lm * 136 + kk * 32 + lq * 8];
        accO = __builtin_amdgcn_mfma_f32_16x16x32_bf16(af, bfr, accO, 0, 0, 0);
      }
#pragma unroll
      for (int kk = 0; kk < 2; kk++) {
        bf16x8 af = *(const bf16x8*)&Atc[(wave * 16 + lm) * 72 + kk * 32 + lq * 8];
        bf16x8 bfr = *(const bf16x8*)&Dt[lm * 72 + kk * 32 + lq * 8];
        accO = __builtin_amdgcn_mfma_f32_16x16x32_bf16(af, bfr, accO, 0, 0, 0);
        bf16x8 afd = *(const bf16x8*)&Dt[lm * 72 + kk * 32 + lq * 8];
#pragma unroll
        for (int j = 0; j < 2; j++) {
          int dt = wave * 2 + j;
          bf16x8 bk = *(const bf16x8*)&Ktc[(dt * 16 + lm) * 72 + kk * 32 + lq * 8];
          accP[j] = __builtin_amdgcn_mfma_f32_16x16x32_bf16(afd, bk, accP[j], 0, 0, 0);
        }
      }
    }
    bar_lds();   // B: phase3 LDS reads complete; chunk buffers may be overwritten

    // write-slot: O -> global (fire-and-forget), state update, store prefetched chunk
#pragma unroll
    for (int r = 0; r < 4; r++) {
      int t = wave * 16 + lq * 4 + r;
      og[(rb + t) * Hm + h * HDd + v0 + lm] = f2bf(accO[r]);
    }
#pragma unroll
    for (int j = 0; j < 2; j++) {
      int dt = wave * 2 + j;
#pragma unroll
      for (int r = 0; r < 4; r++) {
        int vv = lq * 4 + r, d = dt * 16 + lm;
        float ns = St32[vv * 132 + d] + accP[j][r];
        St32[vv * 132 + d] = ns;
        Stb[vv * 136 + d] = f2bf(ns);
      }
    }
#pragma unroll
    for (int j = 0; j < 4; j++) {
      int idx = tid + j * 256;
      int r = idx >> 4, c8 = (idx & 15) * 8;
      *(uint4*)&Wc[r * 136 + c8] = pw[j];
      *(uint4*)&Qc[r * 136 + c8] = pq[j];
      int r2 = idx >> 3, d8 = (idx & 7) * 8;
      *(uint4*)&Ktc[r2 * 72 + d8] = pk[j];
    }
#pragma unroll
    for (int j = 0; j < 2; j++) {
      int idx = tid + j * 256;
      int t = idx >> 3, s8 = (idx & 7) * 8;
      *(uint4*)&Atc[t * 72 + s8] = pa[j];
    }
    if (tid < 128) {
      int t = tid >> 1, c8 = (tid & 1) * 8;
      *(uint4*)&Uc[t * 24 + c8] = pu;
    }
    bar_lds();   // C: new chunk + state visible; og stores NOT drained
  }
}

// ---------------- RMSNorm over head_dim + bf16 in/out ----------------
__global__ __launch_bounds__(256) void rmsn_k(const unsigned short* __restrict__ o,
                                              const float* __restrict__ rw,
                                              unsigned short* __restrict__ ob) {
  int tid = threadIdx.x;
  size_t rowoff = (size_t)blockIdx.x * Hm + tid * 8;
  float f[8];
  ld_bf8(o + rowoff, f);
  float ss = f[0]*f[0] + f[1]*f[1] + f[2]*f[2] + f[3]*f[3] +
             f[4]*f[4] + f[5]*f[5] + f[6]*f[6] + f[7]*f[7];
  ss += __shfl_xor(ss, 1); ss += __shfl_xor(ss, 2); ss += __shfl_xor(ss, 4); ss += __shfl_xor(ss, 8);
  float sc = rsqrtf(ss * (1.f / 128.f) + 1e-5f);
  int d = (tid & 15) * 8;
  float4 wa = *(const float4*)(rw + d);
  float4 wb = *(const float4*)(rw + d + 4);
  ushort4 u0, u1;
  u0.x = f2bf(f[0] * sc * wa.x); u0.y = f2bf(f[1] * sc * wa.y);
  u0.z = f2bf(f[2] * sc * wa.z); u0.w = f2bf(f[3] * sc * wa.w);
  u1.x = f2bf(f[4] * sc * wb.x); u1.y = f2bf(f[5] * sc * wb.y);
  u1.z = f2bf(f[6] * sc * wb.z); u1.w = f2bf(f[7] * sc * wb.w);
  ((ushort4*)ob)[rowoff / 4] = u0;
  ((ushort4*)ob)[rowoff / 4 + 1] = u1;
}

extern "C" void kernel_launch(void* const* d_in, const int* in_sizes, int n_in,
                              void* d_out, int out_size, void* d_ws, size_t ws_size,
                              hipStream_t stream) {
  const float* x  = (const float*)d_in[0];
  const float* Wq = (const float*)d_in[1];
  const float* Wk = (const float*)d_in[2];
  const float* Wv = (const float*)d_in[3];
  const float* Wb = (const float*)d_in[4];
  const float* Wo = (const float*)d_in[5];
  const float* cq = (const float*)d_in[6];
  const float* ck = (const float*)d_in[7];
  const float* cv = (const float*)d_in[8];
  const float* rw = (const float*)d_in[9];

  // d_out (64MB) as scratch: [0:32) xb then o; [32:64) vb. GEMM2 overwrites with fp32 out.
  unsigned short* xb  = (unsigned short*)d_out;
  unsigned short* vb  = (unsigned short*)d_out + (size_t)ROWS * Hm;
  unsigned short* o_b = (unsigned short*)d_out;
  float* out = (float*)d_out;

  // ws: 192.5 MB (proven footprint)
  char* ws = (char*)d_ws;
  size_t off = 0;
  auto alloc = [&](size_t bytes) {
    void* p = ws + off;
    off = (off + bytes + 255) & ~(size_t)255;
    return p;
  };
  unsigned short* wqkv = (unsigned short*)alloc((size_t)QKVN * Hm * 2);   // 24MB
  unsigned short* wob  = (unsigned short*)alloc((size_t)Hm * Hm * 2);     //  8MB
  unsigned short* qkvh = (unsigned short*)alloc((size_t)ROWS * QKVN * 2); // 96MB
  unsigned short* qb   = (unsigned short*)alloc((size_t)ROWS * Hm * 2);   // 32MB
  unsigned short* kb   = (unsigned short*)alloc((size_t)ROWS * Hm * 2);   // 32MB (K, then At in cols [0,64) per chunk)
  float* beta          = (float*)alloc((size_t)ROWS * NHh * 4);           // 0.5MB
  // After conv, qkvh dead: WY buffers alias it (3 x 32MB = 96MB exact)
  unsigned short* Wch = qkvh;                              // [2048][64][128]
  unsigned short* Uch = qkvh + (size_t)2048 * 8192;        // [2048][64][128]
  unsigned short* Kth = qkvh + (size_t)2 * 2048 * 8192;    // [2048][128][64]
  unsigned short* obb = qkvh;  // rmsn out, after recB (W region dead)

  cast_x_k<<<ROWS * Hm / 1024, 256, 0, stream>>>(x, xb);
  cast_w_k<<<Hm * Hm / 256, 256, 0, stream>>>(Wq, Wk, Wv, Wo, wqkv, wob);
  gemm_bt<true><<<dim3(QKVN / 128, ROWS / 128), 256, 0, stream>>>(xb, wqkv, qkvh, ROWS, QKVN, Hm);
  beta_k<<<ROWS / 4, 256, 0, stream>>>(x, Wb, beta);
  conv_k<<<dim3(Hm / 256, Ss / 32, Bb * 3), 256, 0, stream>>>(qkvh, cq, ck, cv, qb, kb, vb);
  recA_k<<<dim3(NC, 32), 256, 0, stream>>>(qb, kb, vb, beta, Wch, Uch, Kth);
  recB_k<<<dim3(8, 32), 256, 0, stream>>>(qb, kb, Wch, Uch, Kth, o_b);
  rmsn_k<<<ROWS, 256, 0, stream>>>(o_b, rw, obb);
  gemm_bt<false><<<dim3(Hm / 128, ROWS / 128), 256, 0, stream>>>(obb, wob, out, ROWS, Hm, Hm);
}

// Round 3
// 963.959 us; speedup vs baseline: 1.2769x; 1.0585x over previous
//
#include <hip/hip_runtime.h>

#define DI __device__ __forceinline__

constexpr int Bb = 2, Ss = 4096, Hm = 2048, NHh = 16, HDd = 128;
constexpr int ROWS = Bb * Ss;   // 8192
constexpr int QKVN = 3 * Hm;    // 6144
constexpr int CC = 64;          // chunk length
constexpr int NC = Ss / CC;     // 64 chunks per (b,h)

typedef __bf16 bf16x8 __attribute__((ext_vector_type(8)));
typedef float f32x4 __attribute__((ext_vector_type(4)));

DI unsigned short f2bf(float f) {
  unsigned int u = __float_as_uint(f);
  u = u + 0x7FFFu + ((u >> 16) & 1u);   // round-to-nearest-even
  return (unsigned short)(u >> 16);
}
DI float bf2f(unsigned int u) { return __uint_as_float(u << 16); }
DI void ld_bf8(const unsigned short* p, float* f) {
  uint4 u = *(const uint4*)p;
  f[0] = bf2f(u.x & 0xffffu); f[1] = bf2f(u.x >> 16);
  f[2] = bf2f(u.y & 0xffffu); f[3] = bf2f(u.y >> 16);
  f[4] = bf2f(u.z & 0xffffu); f[5] = bf2f(u.z >> 16);
  f[6] = bf2f(u.w & 0xffffu); f[7] = bf2f(u.w >> 16);
}

// async global->LDS, 16B/lane, lds dest = base + lane*16 (wave-uniform base)
DI void gld16(const unsigned short* g, unsigned short* l) {
  __builtin_amdgcn_global_load_lds(
      (const __attribute__((address_space(1))) unsigned int*)g,
      (__attribute__((address_space(3))) unsigned int*)l, 16, 0, 0);
}

// raw barrier with LDS-only drain: does NOT wait vmcnt (global loads/stores
// stay in flight across the barrier — T4 counted-vmcnt discipline).
DI void bar_lds() {
  asm volatile("s_waitcnt lgkmcnt(0)" ::: "memory");
  __builtin_amdgcn_s_barrier();
}

// ---------------- cast x -> bf16 ----------------
__global__ void cast_x_k(const float* __restrict__ x, unsigned short* __restrict__ xb) {
  int i = blockIdx.x * 256 + threadIdx.x;
  float4 f = ((const float4*)x)[i];
  ushort4 u;
  u.x = f2bf(f.x); u.y = f2bf(f.y); u.z = f2bf(f.z); u.w = f2bf(f.w);
  ((ushort4*)xb)[i] = u;
}

// ---------------- cast weights -> bf16 (Wq|Wk|Wv concat, Wo) ----------------
__global__ void cast_w_k(const float* __restrict__ Wq, const float* __restrict__ Wk,
                         const float* __restrict__ Wv, const float* __restrict__ Wo,
                         unsigned short* __restrict__ wqkv, unsigned short* __restrict__ wo) {
  const int W1 = Hm * Hm;
  int idx = blockIdx.x * 256 + threadIdx.x;
  for (int r = 0; r < 4; r++) {
    int i = idx + r * W1;
    if (i < W1)            wqkv[i] = f2bf(Wq[i]);
    else if (i < 2 * W1)   wqkv[i] = f2bf(Wk[i - W1]);
    else if (i < 3 * W1)   wqkv[i] = f2bf(Wv[i - 2 * W1]);
    else                   wo[i - 3 * W1] = f2bf(Wo[i - 3 * W1]);
  }
}

// ---------------- 256x256 8-phase bf16 NT GEMM (T1+T2+T3+T4+T5) ----------------
// 512 thr = 8 waves (2M x 4N); BK=64; LDS 128KiB double-buffered.
// T2 swizzle: logical (r,c16) stored at phys slot c16^(r&7) (16B units) — applied
// via inverse-swizzled GLOBAL source (linear LDS dest for global_load_lds) and
// swizzled ds_read. Staging schedule writes only into dead regions:
//   B-halves of buf die after ph1 reads; A-halves after ph2 reads.
//   ph0: A0(t+1)->nxt  ph1: A1(t+1)->nxt  ph2: B0(t+2)->cur  ph3: B1(t+2)->cur
// Single counted vmcnt(4) per K-tile at ph3 (never drains to 0 in-loop).
DI bf16x8 ldsw(const unsigned short* base, int r, int c16) {
  return *(const bf16x8*)&base[r * 64 + ((c16 ^ (r & 7)) << 3)];
}

template <bool BF16_OUT>
__global__ __launch_bounds__(512) void gemm256(const unsigned short* __restrict__ A,
                                               const unsigned short* __restrict__ Bm,
                                               void* __restrict__ Cout,
                                               int M, int N, int Kd) {
  __shared__ __align__(16) unsigned short As[2][16384];
  __shared__ __align__(16) unsigned short Bs[2][16384];
  int tid = threadIdx.x;
  int wave = tid >> 6, lane = tid & 63;
  int lm = lane & 15, lq = lane >> 4;
  int wm = (wave >> 2) * 128, wn = (wave & 3) * 64;

  // T1: bijective XCD swizzle (nwg % 8 == 0 for both call sites)
  int nx = N >> 8;
  int nwg = gridDim.x * gridDim.y;
  int lin = blockIdx.x + gridDim.x * blockIdx.y;
  int cpx = nwg >> 3;
  int swz = (lin & 7) * cpx + (lin >> 3);
  int bn = (swz % nx) << 8, bm = (swz / nx) << 8;

  int NT = Kd >> 6;
  // staging constants: lane covers phys 16B slot (l&7) of row-block offset (l>>3);
  // inverse swizzle: source col16 = (l&7) ^ (l>>3)
  int rsub = lane >> 3;
  int csw = ((lane & 7) ^ rsub) << 3;   // in shorts

  auto stageA = [&](int buf, int half, int ts) {
    int ksrc = (ts < NT ? ts : NT - 1) << 6;
#pragma unroll
    for (int i = 0; i < 2; i++) {
      int blk = wave * 2 + i;
      int r = half * 128 + blk * 8 + rsub;
      gld16(&A[(size_t)(bm + r) * Kd + ksrc + csw], &As[buf][half * 8192 + blk * 512]);
    }
  };
  auto stageB = [&](int buf, int half, int ts) {
    int ksrc = (ts < NT ? ts : NT - 1) << 6;
#pragma unroll
    for (int i = 0; i < 2; i++) {
      int blk = wave * 2 + i;
      int r = half * 128 + blk * 8 + rsub;
      gld16(&Bm[(size_t)(bn + r) * Kd + ksrc + csw], &Bs[buf][half * 8192 + blk * 512]);
    }
  };

  f32x4 acc[8][4] = {};
  bf16x8 a[4][2], b[4][2];

  // prologue: tile0 fully + B of tile1; wait tile0 (leave 4 loads in flight)
  stageA(0, 0, 0); stageA(0, 1, 0); stageB(0, 0, 0); stageB(0, 1, 0);
  stageB(1, 0, 1); stageB(1, 1, 1);
  asm volatile("s_waitcnt vmcnt(4)" ::: "memory");
  __builtin_amdgcn_s_barrier();

  for (int t = 0; t < NT; t++) {
    int cur = t & 1, nxt = cur ^ 1;
    const unsigned short* Ac = As[cur];
    const unsigned short* Bc = Bs[cur];

    // ---- ph0: read A lo (fi0-3) + B lo (fj0-1); stage A0(t+1); MFMA Q(lo,lo)
#pragma unroll
    for (int fi = 0; fi < 4; fi++)
#pragma unroll
      for (int kk = 0; kk < 2; kk++)
        a[fi][kk] = ldsw(Ac, wm + fi * 16 + lm, kk * 4 + lq);
#pragma unroll
    for (int fj = 0; fj < 2; fj++)
#pragma unroll
      for (int kk = 0; kk < 2; kk++)
        b[fj][kk] = ldsw(Bc, wn + fj * 16 + lm, kk * 4 + lq);
    stageA(nxt, 0, t + 1);
    asm volatile("" ::: "memory");
    __builtin_amdgcn_s_barrier();
    asm volatile("s_waitcnt lgkmcnt(0)" ::: "memory");
    __builtin_amdgcn_sched_barrier(0);
    __builtin_amdgcn_s_setprio(1);
#pragma unroll
    for (int kk = 0; kk < 2; kk++)
#pragma unroll
      for (int fi = 0; fi < 4; fi++)
#pragma unroll
        for (int fj = 0; fj < 2; fj++)
          acc[fi][fj] = __builtin_amdgcn_mfma_f32_16x16x32_bf16(a[fi][kk], b[fj][kk], acc[fi][fj], 0, 0, 0);
    __builtin_amdgcn_s_setprio(0);
    asm volatile("" ::: "memory");
    __builtin_amdgcn_s_barrier();

    // ---- ph1: read B hi (fj2-3); stage A1(t+1); MFMA Q(lo,hi)
#pragma unroll
    for (int fj = 0; fj < 2; fj++)
#pragma unroll
      for (int kk = 0; kk < 2; kk++)
        b[2 + fj][kk] = ldsw(Bc, wn + (2 + fj) * 16 + lm, kk * 4 + lq);
    stageA(nxt, 1, t + 1);
    asm volatile("" ::: "memory");
    __builtin_amdgcn_s_barrier();
    asm volatile("s_waitcnt lgkmcnt(0)" ::: "memory");
    __builtin_amdgcn_sched_barrier(0);
    __builtin_amdgcn_s_setprio(1);
#pragma unroll
    for (int kk = 0; kk < 2; kk++)
#pragma unroll
      for (int fi = 0; fi < 4; fi++)
#pragma unroll
        for (int fj = 0; fj < 2; fj++)
          acc[fi][2 + fj] = __builtin_amdgcn_mfma_f32_16x16x32_bf16(a[fi][kk], b[2 + fj][kk], acc[fi][2 + fj], 0, 0, 0);
    __builtin_amdgcn_s_setprio(0);
    asm volatile("" ::: "memory");
    __builtin_amdgcn_s_barrier();

    // ---- ph2: read A hi (fi4-7, reuse a[]); stage B0(t+2) (B of cur died ph1); MFMA Q(hi,hi)
#pragma unroll
    for (int fi = 0; fi < 4; fi++)
#pragma unroll
      for (int kk = 0; kk < 2; kk++)
        a[fi][kk] = ldsw(Ac, wm + 64 + fi * 16 + lm, kk * 4 + lq);
    stageB(cur, 0, t + 2);
    asm volatile("" ::: "memory");
    __builtin_amdgcn_s_barrier();
    asm volatile("s_waitcnt lgkmcnt(0)" ::: "memory");
    __builtin_amdgcn_sched_barrier(0);
    __builtin_amdgcn_s_setprio(1);
#pragma unroll
    for (int kk = 0; kk < 2; kk++)
#pragma unroll
      for (int fi = 0; fi < 4; fi++)
#pragma unroll
        for (int fj = 0; fj < 2; fj++)
          acc[4 + fi][2 + fj] = __builtin_amdgcn_mfma_f32_16x16x32_bf16(a[fi][kk], b[2 + fj][kk], acc[4 + fi][2 + fj], 0, 0, 0);
    __builtin_amdgcn_s_setprio(0);
    asm volatile("" ::: "memory");
    __builtin_amdgcn_s_barrier();

    // ---- ph3: no ds_reads; stage B1(t+2); MFMA Q(hi,lo); vmcnt(4) gates tile t+1
    stageB(cur, 1, t + 2);
    asm volatile("" ::: "memory");
    __builtin_amdgcn_s_barrier();
    __builtin_amdgcn_s_setprio(1);
#pragma unroll
    for (int kk = 0; kk < 2; kk++)
#pragma unroll
      for (int fi = 0; fi < 4; fi++)
#pragma unroll
        for (int fj = 0; fj < 2; fj++)
          acc[4 + fi][fj] = __builtin_amdgcn_mfma_f32_16x16x32_bf16(a[fi][kk], b[fj][kk], acc[4 + fi][fj], 0, 0, 0);
    __builtin_amdgcn_s_setprio(0);
    asm volatile("s_waitcnt vmcnt(4)" ::: "memory");
    __builtin_amdgcn_s_barrier();
  }

  // epilogue
#pragma unroll
  for (int fi = 0; fi < 8; fi++)
#pragma unroll
    for (int fj = 0; fj < 4; fj++) {
      int row = bm + wm + fi * 16 + lq * 4;
      int col = bn + wn + fj * 16 + lm;
#pragma unroll
      for (int r = 0; r < 4; r++) {
        if (BF16_OUT)
          ((unsigned short*)Cout)[(size_t)(row + r) * N + col] = f2bf(acc[fi][fj][r]);
        else
          ((float*)Cout)[(size_t)(row + r) * N + col] = acc[fi][fj][r];
      }
    }
}

// ---------------- causal conv K=4 + silu + (l2norm for q/k), bf16 in/out ----------------
__global__ __launch_bounds__(256) void conv_k(const unsigned short* __restrict__ qkvh,
                                              const float* __restrict__ cwq,
                                              const float* __restrict__ cwk,
                                              const float* __restrict__ cwv,
                                              unsigned short* __restrict__ qb,
                                              unsigned short* __restrict__ kb,
                                              unsigned short* __restrict__ vb) {
  __shared__ __align__(16) float sm[32 * 260];   // pad 260: bank stride 4, not 0
  __shared__ float fac[64];
  int tid = threadIdx.x;
  int cblk = blockIdx.x * 256;
  int s0 = blockIdx.y * 32;
  int z = blockIdx.z;
  int sel = z >> 1, b = z & 1;
  const float* cw = sel == 0 ? cwq : (sel == 1 ? cwk : cwv);
  int c = cblk + tid;
  float4 w = ((const float4*)cw)[c];
  const unsigned short* in = qkvh + (size_t)b * Ss * QKVN + sel * Hm + c;
  float x0 = (s0 >= 3) ? bf2f(in[(size_t)(s0 - 3) * QKVN]) : 0.f;
  float x1 = (s0 >= 2) ? bf2f(in[(size_t)(s0 - 2) * QKVN]) : 0.f;
  float x2 = (s0 >= 1) ? bf2f(in[(size_t)(s0 - 1) * QKVN]) : 0.f;
  for (int si = 0; si < 32; si++) {
    float x3 = bf2f(in[(size_t)(s0 + si) * QKVN]);
    float a = w.x * x0 + w.y * x1 + w.z * x2 + w.w * x3;
    sm[si * 260 + tid] = a / (1.f + __expf(-a));
    x0 = x1; x1 = x2; x2 = x3;
  }
  __syncthreads();
  if (sel < 2) {
    int si = tid >> 3, p = tid & 7;
    const float* row = &sm[si * 260 + p * 32];
    float ss = 0.f;
#pragma unroll
    for (int j = 0; j < 32; j += 4) {
      float4 v4 = *(const float4*)(row + j);
      ss += v4.x * v4.x + v4.y * v4.y + v4.z * v4.z + v4.w * v4.w;
    }
    ss += __shfl_xor(ss, 1);
    ss += __shfl_xor(ss, 2);
    float f = rsqrtf(ss + 1e-6f);
    if (sel == 0) f *= 0.08838834764831845f;
    if ((p & 3) == 0) fac[si * 2 + (p >> 2)] = f;
  }
  __syncthreads();
  unsigned short* outp = sel == 0 ? qb : (sel == 1 ? kb : vb);
  int hl = tid >> 7;
  for (int si = 0; si < 32; si++) {
    float val = sm[si * 260 + tid];
    if (sel < 2) val *= fac[si * 2 + hl];
    outp[(size_t)(b * Ss + s0 + si) * Hm + cblk + tid] = f2bf(val);
  }
}

// ---------------- beta = sigmoid(x @ Wb^T), fp32 ----------------
__global__ __launch_bounds__(256) void beta_k(const float* __restrict__ x,
                                              const float* __restrict__ Wbm,
                                              float* __restrict__ beta) {
  int wid = threadIdx.x >> 6, lane = threadIdx.x & 63;
  int row = blockIdx.x * 4 + wid;
  int h = lane & 15, part = lane >> 4;
  const float* xr = x + (size_t)row * Hm + part * 512;
  const float* wr = Wbm + (size_t)h * Hm + part * 512;
  float acc = 0.f;
  for (int j = 0; j < 512; j += 4) {
    float4 xv = *(const float4*)(xr + j);
    float4 wv = *(const float4*)(wr + j);
    acc += xv.x * wv.x + xv.y * wv.y + xv.z * wv.z + xv.w * wv.w;
  }
  acc += __shfl_xor(acc, 16);
  acc += __shfl_xor(acc, 32);
  if (part == 0) beta[(size_t)row * NHh + h] = 1.f / (1.f + __expf(-acc));
}

// ---------------- recA: per-chunk WY precompute + At, doubling-based inverse ----------------
// grid (NC, 32). Outputs: W[cid][t][d], U[cid][t][v], Kt[cid][d][s]; At into kg's own chunk cols [0,64)
__global__ __launch_bounds__(256) void recA_k(const unsigned short* __restrict__ qg,
                                              unsigned short* kg,   // read K, write At
                                              const unsigned short* __restrict__ vg,
                                              const float* __restrict__ beta,
                                              unsigned short* __restrict__ Wo_,
                                              unsigned short* __restrict__ Uo,
                                              unsigned short* __restrict__ Kto) {
  __shared__ __align__(16) unsigned short Kc[64 * 136];
  __shared__ __align__(16) unsigned short Qc[64 * 136];
  __shared__ __align__(16) unsigned short Vt[128 * 72];
  __shared__ __align__(16) unsigned short Kt[128 * 72];
  __shared__ __align__(16) unsigned short Xa[64 * 72], Xat[64 * 72];
  __shared__ __align__(16) unsigned short Xb2[64 * 72], Xbt[64 * 72];
  __shared__ __align__(16) unsigned short Pa[64 * 72], Pb[64 * 72];
  __shared__ float bl[64];
  int tid = threadIdx.x;
  int c = blockIdx.x, bh = blockIdx.y;
  int b = bh >> 4, h = bh & 15;
  size_t cid = (size_t)bh * NC + c;
  size_t rowbase = (size_t)b * Ss + (size_t)c * CC;
  int wave = tid >> 6, lane = tid & 63, lm = lane & 15, lq = lane >> 4;

  // stage K, Q chunks (16B), V transposed (scalar), beta
  for (int idx = tid; idx < 1024; idx += 256) {
    int r = idx >> 4, c8 = (idx & 15) * 8;
    *(uint4*)&Kc[r * 136 + c8] = *(const uint4*)&kg[(rowbase + r) * Hm + h * HDd + c8];
    *(uint4*)&Qc[r * 136 + c8] = *(const uint4*)&qg[(rowbase + r) * Hm + h * HDd + c8];
  }
  for (int idx = tid; idx < 8192; idx += 256) {
    int s = idx >> 7, vv = idx & 127;
    Vt[vv * 72 + s] = vg[(rowbase + s) * Hm + h * HDd + vv];
  }
  if (tid < 64) bl[tid] = beta[(rowbase + tid) * NHh + h];
  __syncthreads();

  // Kt = K^T (LDS transpose)
  for (int idx = tid; idx < 8192; idx += 256) {
    int s = idx >> 7, d = idx & 127;
    Kt[d * 72 + s] = Kc[s * 136 + d];
  }
  // accA = K K^T -> M = -strict_tril(diag(beta) K K^T); write M, M^T, P0 = I + M
  {
    f32x4 accA[4] = {};
#pragma unroll
    for (int kk = 0; kk < 4; kk++) {
      bf16x8 af = *(const bf16x8*)&Kc[(wave * 16 + lm) * 136 + kk * 32 + lq * 8];
#pragma unroll
      for (int st = 0; st < 4; st++) {
        bf16x8 bfr = *(const bf16x8*)&Kc[(st * 16 + lm) * 136 + kk * 32 + lq * 8];
        accA[st] = __builtin_amdgcn_mfma_f32_16x16x32_bf16(af, bfr, accA[st], 0, 0, 0);
      }
    }
#pragma unroll
    for (int st = 0; st < 4; st++)
#pragma unroll
      for (int r = 0; r < 4; r++) {
        int t = wave * 16 + lq * 4 + r, s = st * 16 + lm;
        float m = (t > s) ? -bl[t] * accA[st][r] : 0.f;
        unsigned short mb = f2bf(m);
        Xa[t * 72 + s] = mb;
        Xat[s * 72 + t] = mb;
        Pa[t * 72 + s] = (t == s) ? f2bf(1.f) : mb;
      }
  }
  // At = mask(Q K^T) written into kg's own chunk region cols [0,64)
  {
    f32x4 accQ[4] = {};
#pragma unroll
    for (int kk = 0; kk < 4; kk++) {
      bf16x8 af = *(const bf16x8*)&Qc[(wave * 16 + lm) * 136 + kk * 32 + lq * 8];
#pragma unroll
      for (int st = 0; st < 4; st++) {
        bf16x8 bfr = *(const bf16x8*)&Kc[(st * 16 + lm) * 136 + kk * 32 + lq * 8];
        accQ[st] = __builtin_amdgcn_mfma_f32_16x16x32_bf16(af, bfr, accQ[st], 0, 0, 0);
      }
    }
#pragma unroll
    for (int st = 0; st < 4; st++)
#pragma unroll
      for (int r = 0; r < 4; r++) {
        int t = wave * 16 + lq * 4 + r, s = st * 16 + lm;
        kg[(rowbase + t) * Hm + h * HDd + s] = (s <= t) ? f2bf(accQ[st][r]) : (unsigned short)0;
      }
  }
  __syncthreads();

  // doubling: T = (I-M)^-1 = prod_{k=0..5} (I + M^(2^k)); carry (X, X^T) pairs
  unsigned short *X = Xa, *Xt = Xat, *Xn = Xb2, *Xnt = Xbt, *P = Pa, *Pn = Pb;
  for (int lvl = 1; lvl <= 5; lvl++) {
    // Xn = NT(X, Xt) = X*X ; Xnt = NT(Xt, X) = (X*X)^T
    f32x4 a1[4] = {}, a2[4] = {};
#pragma unroll
    for (int kk = 0; kk < 2; kk++) {
      bf16x8 afx  = *(const bf16x8*)&X[(wave * 16 + lm) * 72 + kk * 32 + lq * 8];
      bf16x8 afxt = *(const bf16x8*)&Xt[(wave * 16 + lm) * 72 + kk * 32 + lq * 8];
#pragma unroll
      for (int st = 0; st < 4; st++) {
        bf16x8 bx  = *(const bf16x8*)&X[(st * 16 + lm) * 72 + kk * 32 + lq * 8];
        bf16x8 bxt = *(const bf16x8*)&Xt[(st * 16 + lm) * 72 + kk * 32 + lq * 8];
        a1[st] = __builtin_amdgcn_mfma_f32_16x16x32_bf16(afx, bxt, a1[st], 0, 0, 0);
        a2[st] = __builtin_amdgcn_mfma_f32_16x16x32_bf16(afxt, bx, a2[st], 0, 0, 0);
      }
    }
#pragma unroll
    for (int st = 0; st < 4; st++)
#pragma unroll
      for (int r = 0; r < 4; r++) {
        int t = wave * 16 + lq * 4 + r, s = st * 16 + lm;
        Xn[t * 72 + s]  = f2bf(a1[st][r]);
        Xnt[t * 72 + s] = f2bf(a2[st][r]);
      }
    __syncthreads();
    // Pn = P + P*Xn = NT(P, Xnt) with acc seeded by P
    f32x4 ap[4];
#pragma unroll
    for (int st = 0; st < 4; st++)
#pragma unroll
      for (int r = 0; r < 4; r++)
        ap[st][r] = bf2f(P[(wave * 16 + lq * 4 + r) * 72 + st * 16 + lm]);
#pragma unroll
    for (int kk = 0; kk < 2; kk++) {
      bf16x8 afp = *(const bf16x8*)&P[(wave * 16 + lm) * 72 + kk * 32 + lq * 8];
#pragma unroll
      for (int st = 0; st < 4; st++) {
        bf16x8 bxnt = *(const bf16x8*)&Xnt[(st * 16 + lm) * 72 + kk * 32 + lq * 8];
        ap[st] = __builtin_amdgcn_mfma_f32_16x16x32_bf16(afp, bxnt, ap[st], 0, 0, 0);
      }
    }
#pragma unroll
    for (int st = 0; st < 4; st++)
#pragma unroll
      for (int r = 0; r < 4; r++) {
        int t = wave * 16 + lq * 4 + r, s = st * 16 + lm;
        // last level: fold in diag(beta) -> Tb
        Pn[t * 72 + s] = f2bf((lvl == 5) ? ap[st][r] * bl[s] : ap[st][r]);
      }
    // swap
    unsigned short* tmp;
    tmp = X; X = Xn; Xn = tmp;
    tmp = Xt; Xt = Xnt; Xnt = tmp;
    tmp = P; P = Pn; Pn = tmp;
    __syncthreads();
  }

  // store Kt to global
  for (int idx = tid; idx < 1024; idx += 256) {
    int d = idx >> 3, s8 = (idx & 7) * 8;
    *(uint4*)&Kto[cid * 8192 + d * 64 + s8] = *(const uint4*)&Kt[d * 72 + s8];
  }
  // U = NT(Tb, Vt) ; W = NT(Tb, Kt)   (Tb = P)
  {
    unsigned short* Up = Uo + cid * 8192;
    unsigned short* Wp = Wo_ + cid * 8192;
    f32x4 accU[8] = {}, accW[8] = {};
#pragma unroll
    for (int kk = 0; kk < 2; kk++) {
      bf16x8 af = *(const bf16x8*)&P[(wave * 16 + lm) * 72 + kk * 32 + lq * 8];
#pragma unroll
      for (int nt = 0; nt < 8; nt++) {
        bf16x8 bv = *(const bf16x8*)&Vt[(nt * 16 + lm) * 72 + kk * 32 + lq * 8];
        bf16x8 bk = *(const bf16x8*)&Kt[(nt * 16 + lm) * 72 + kk * 32 + lq * 8];
        accU[nt] = __builtin_amdgcn_mfma_f32_16x16x32_bf16(af, bv, accU[nt], 0, 0, 0);
        accW[nt] = __builtin_amdgcn_mfma_f32_16x16x32_bf16(af, bk, accW[nt], 0, 0, 0);
      }
    }
#pragma unroll
    for (int nt = 0; nt < 8; nt++)
#pragma unroll
      for (int r = 0; r < 4; r++) {
        int t = wave * 16 + lq * 4 + r, n = nt * 16 + lm;
        Up[t * 128 + n] = f2bf(accU[nt][r]);
        Wp[t * 128 + n] = f2bf(accW[nt][r]);
      }
  }
}

// ---------------- recB: sequential chunk scan, 256 WGs (8 v-slices x 32 bh) ----------------
__global__ __launch_bounds__(256) void recB_k(const unsigned short* __restrict__ qg,
                                              const unsigned short* __restrict__ atg,
                                              const unsigned short* __restrict__ Wg,
                                              const unsigned short* __restrict__ Ug,
                                              const unsigned short* __restrict__ Ktg,
                                              unsigned short* __restrict__ og) {
  __shared__ __align__(16) unsigned short Wc[64 * 136];
  __shared__ __align__(16) unsigned short Qc[64 * 136];
  __shared__ __align__(16) unsigned short Ktc[128 * 72];
  __shared__ __align__(16) unsigned short Atc[64 * 72];
  __shared__ __align__(16) unsigned short Uc[64 * 24];
  __shared__ __align__(16) unsigned short Dt[16 * 72];
  __shared__ __align__(16) unsigned short Stb[16 * 136];
  __shared__ float St32[16 * 132];
  int tid = threadIdx.x;
  // XCD-aware swizzle: all 8 v-slices of one (b,h) on the same XCD (id%8).
  int lin = blockIdx.x + (blockIdx.y << 3);
  int xcd = lin & 7, slot = lin >> 3;
  int vs = slot & 7;
  int bh = xcd + ((slot >> 3) << 3);
  int b = bh >> 4, h = bh & 15, v0 = vs * 16;
  int wave = tid >> 6, lane = tid & 63, lm = lane & 15, lq = lane >> 4;

  for (int i = tid; i < 16 * 132; i += 256) St32[i] = 0.f;
  for (int i = tid; i < 16 * 136; i += 256) Stb[i] = 0;

  // prologue: stage chunk 0 directly
  {
    size_t cid0 = (size_t)bh * NC;
    size_t rb0 = (size_t)b * Ss;
    const unsigned short* Wp = Wg + cid0 * 8192;
    const unsigned short* Ktp = Ktg + cid0 * 8192;
    const unsigned short* Up = Ug + cid0 * 8192 + v0;
#pragma unroll
    for (int j = 0; j < 4; j++) {
      int idx = tid + j * 256;
      int r = idx >> 4, c8 = (idx & 15) * 8;
      *(uint4*)&Wc[r * 136 + c8] = *(const uint4*)&Wp[r * 128 + c8];
      *(uint4*)&Qc[r * 136 + c8] = *(const uint4*)&qg[(rb0 + r) * Hm + h * HDd + c8];
      int r2 = idx >> 3, d8 = (idx & 7) * 8;
      *(uint4*)&Ktc[r2 * 72 + d8] = *(const uint4*)&Ktp[r2 * 64 + d8];
    }
#pragma unroll
    for (int j = 0; j < 2; j++) {
      int idx = tid + j * 256;
      int t = idx >> 3, s8 = (idx & 7) * 8;
      *(uint4*)&Atc[t * 72 + s8] = *(const uint4*)&atg[(rb0 + t) * Hm + h * HDd + s8];
    }
    if (tid < 128) {
      int t = tid >> 1, c8 = (tid & 1) * 8;
      *(uint4*)&Uc[t * 24 + c8] = *(const uint4*)&Up[t * 128 + c8];
    }
  }
  __syncthreads();

  for (int c = 0; c < NC; c++) {
    size_t rb = (size_t)b * Ss + (size_t)c * CC;
    // issue prefetch of chunk c+1 into registers (consumed in write-slot).
    // With bar_lds() these loads stay in flight across BOTH phase barriers;
    // the only wait is the compiler's counted vmcnt at first register use.
    int cn = (c + 1 < NC) ? c + 1 : c;
    size_t cidn = (size_t)bh * NC + cn;
    size_t rbn = (size_t)b * Ss + (size_t)cn * CC;
    const unsigned short* Wpn = Wg + cidn * 8192;
    const unsigned short* Ktpn = Ktg + cidn * 8192;
    const unsigned short* Upn = Ug + cidn * 8192 + v0;
    uint4 pw[4], pq[4], pk[4], pa[2], pu;
#pragma unroll
    for (int j = 0; j < 4; j++) {
      int idx = tid + j * 256;
      int r = idx >> 4, c8 = (idx & 15) * 8;
      pw[j] = *(const uint4*)&Wpn[r * 128 + c8];
      pq[j] = *(const uint4*)&qg[(rbn + r) * Hm + h * HDd + c8];
      int r2 = idx >> 3, d8 = (idx & 7) * 8;
      pk[j] = *(const uint4*)&Ktpn[r2 * 64 + d8];
    }
#pragma unroll
    for (int j = 0; j < 2; j++) {
      int idx = tid + j * 256;
      int t = idx >> 3, s8 = (idx & 7) * 8;
      pa[j] = *(const uint4*)&atg[(rbn + t) * Hm + h * HDd + s8];
    }
    if (tid < 128) {
      int t = tid >> 1, c8 = (tid & 1) * 8;
      pu = *(const uint4*)&Upn[t * 128 + c8];
    }

    // phase2: accD = NT(Wc, Stb) [64t x 16v]; Dt[v][t] = U - accD
    {
      f32x4 accD = {};
#pragma unroll
      for (int kk = 0; kk < 4; kk++) {
        bf16x8 af = *(const bf16x8*)&Wc[(wave * 16 + lm) * 136 + kk * 32 + lq * 8];
        bf16x8 bfr = *(const bf16x8*)&Stb[lm * 136 + kk * 32 + lq * 8];
        accD = __builtin_amdgcn_mfma_f32_16x16x32_bf16(af, bfr, accD, 0, 0, 0);
      }
#pragma unroll
      for (int r = 0; r < 4; r++) {
        int t = wave * 16 + lq * 4 + r;
        float dv = bf2f(Uc[t * 24 + lm]) - accD[r];
        Dt[lm * 72 + t] = f2bf(dv);
      }
    }
    bar_lds();   // A: Dt visible; prefetch loads remain in flight

    // phase3+4 fused: accO = NT(Qc,Stb) + NT(Atc,Dt); accP = NT(Dt,Ktc)
    f32x4 accO = {};
    f32x4 accP[2] = {};
    {
#pragma unroll
      for (int kk = 0; kk < 4; kk++) {
        bf16x8 af = *(const bf16x8*)&Qc[(wave * 16 + lm) * 136 + kk * 32 + lq * 8];
        bf16x8 bfr = *(const bf16x8*)&Stb[lm * 136 + kk * 32 + lq * 8];
        accO = __builtin_amdgcn_mfma_f32_16x16x32_bf16(af, bfr, accO, 0, 0, 0);
      }
#pragma unroll
      for (int kk = 0; kk < 2; kk++) {
        bf16x8 af = *(const bf16x8*)&Atc[(wave * 16 + lm) * 72 + kk * 32 + lq * 8];
        bf16x8 bfr = *(const bf16x8*)&Dt[lm * 72 + kk * 32 + lq * 8];
        accO = __builtin_amdgcn_mfma_f32_16x16x32_bf16(af, bfr, accO, 0, 0, 0);
        bf16x8 afd = *(const bf16x8*)&Dt[lm * 72 + kk * 32 + lq * 8];
#pragma unroll
        for (int j = 0; j < 2; j++) {
          int dt = wave * 2 + j;
          bf16x8 bk = *(const bf16x8*)&Ktc[(dt * 16 + lm) * 72 + kk * 32 + lq * 8];
          accP[j] = __builtin_amdgcn_mfma_f32_16x16x32_bf16(afd, bk, accP[j], 0, 0, 0);
        }
      }
    }
    bar_lds();   // B: phase3 LDS reads complete; chunk buffers may be overwritten

    // write-slot: O -> global (fire-and-forget), state update, store prefetched chunk
#pragma unroll
    for (int r = 0; r < 4; r++) {
      int t = wave * 16 + lq * 4 + r;
      og[(rb + t) * Hm + h * HDd + v0 + lm] = f2bf(accO[r]);
    }
#pragma unroll
    for (int j = 0; j < 2; j++) {
      int dt = wave * 2 + j;
#pragma unroll
      for (int r = 0; r < 4; r++) {
        int vv = lq * 4 + r, d = dt * 16 + lm;
        float ns = St32[vv * 132 + d] + accP[j][r];
        St32[vv * 132 + d] = ns;
        Stb[vv * 136 + d] = f2bf(ns);
      }
    }
#pragma unroll
    for (int j = 0; j < 4; j++) {
      int idx = tid + j * 256;
      int r = idx >> 4, c8 = (idx & 15) * 8;
      *(uint4*)&Wc[r * 136 + c8] = pw[j];
      *(uint4*)&Qc[r * 136 + c8] = pq[j];
      int r2 = idx >> 3, d8 = (idx & 7) * 8;
      *(uint4*)&Ktc[r2 * 72 + d8] = pk[j];
    }
#pragma unroll
    for (int j = 0; j < 2; j++) {
      int idx = tid + j * 256;
      int t = idx >> 3, s8 = (idx & 7) * 8;
      *(uint4*)&Atc[t * 72 + s8] = pa[j];
    }
    if (tid < 128) {
      int t = tid >> 1, c8 = (tid & 1) * 8;
      *(uint4*)&Uc[t * 24 + c8] = pu;
    }
    bar_lds();   // C: new chunk + state visible; og stores NOT drained
  }
}

// ---------------- RMSNorm over head_dim + bf16 in/out ----------------
__global__ __launch_bounds__(256) void rmsn_k(const unsigned short* __restrict__ o,
                                              const float* __restrict__ rw,
                                              unsigned short* __restrict__ ob) {
  int tid = threadIdx.x;
  size_t rowoff = (size_t)blockIdx.x * Hm + tid * 8;
  float f[8];
  ld_bf8(o + rowoff, f);
  float ss = f[0]*f[0] + f[1]*f[1] + f[2]*f[2] + f[3]*f[3] +
             f[4]*f[4] + f[5]*f[5] + f[6]*f[6] + f[7]*f[7];
  ss += __shfl_xor(ss, 1); ss += __shfl_xor(ss, 2); ss += __shfl_xor(ss, 4); ss += __shfl_xor(ss, 8);
  float sc = rsqrtf(ss * (1.f / 128.f) + 1e-5f);
  int d = (tid & 15) * 8;
  float4 wa = *(const float4*)(rw + d);
  float4 wb = *(const float4*)(rw + d + 4);
  ushort4 u0, u1;
  u0.x = f2bf(f[0] * sc * wa.x); u0.y = f2bf(f[1] * sc * wa.y);
  u0.z = f2bf(f[2] * sc * wa.z); u0.w = f2bf(f[3] * sc * wa.w);
  u1.x = f2bf(f[4] * sc * wb.x); u1.y = f2bf(f[5] * sc * wb.y);
  u1.z = f2bf(f[6] * sc * wb.z); u1.w = f2bf(f[7] * sc * wb.w);
  ((ushort4*)ob)[rowoff / 4] = u0;
  ((ushort4*)ob)[rowoff / 4 + 1] = u1;
}

extern "C" void kernel_launch(void* const* d_in, const int* in_sizes, int n_in,
                              void* d_out, int out_size, void* d_ws, size_t ws_size,
                              hipStream_t stream) {
  const float* x  = (const float*)d_in[0];
  const float* Wq = (const float*)d_in[1];
  const float* Wk = (const float*)d_in[2];
  const float* Wv = (const float*)d_in[3];
  const float* Wb = (const float*)d_in[4];
  const float* Wo = (const float*)d_in[5];
  const float* cq = (const float*)d_in[6];
  const float* ck = (const float*)d_in[7];
  const float* cv = (const float*)d_in[8];
  const float* rw = (const float*)d_in[9];

  // d_out (64MB) as scratch: [0:32) xb then o; [32:64) vb. GEMM2 overwrites with fp32 out.
  unsigned short* xb  = (unsigned short*)d_out;
  unsigned short* vb  = (unsigned short*)d_out + (size_t)ROWS * Hm;
  unsigned short* o_b = (unsigned short*)d_out;
  float* out = (float*)d_out;

  // ws: 192.5 MB (proven footprint)
  char* ws = (char*)d_ws;
  size_t off = 0;
  auto alloc = [&](size_t bytes) {
    void* p = ws + off;
    off = (off + bytes + 255) & ~(size_t)255;
    return p;
  };
  unsigned short* wqkv = (unsigned short*)alloc((size_t)QKVN * Hm * 2);   // 24MB
  unsigned short* wob  = (unsigned short*)alloc((size_t)Hm * Hm * 2);     //  8MB
  unsigned short* qkvh = (unsigned short*)alloc((size_t)ROWS * QKVN * 2); // 96MB
  unsigned short* qb   = (unsigned short*)alloc((size_t)ROWS * Hm * 2);   // 32MB
  unsigned short* kb   = (unsigned short*)alloc((size_t)ROWS * Hm * 2);   // 32MB (K, then At in cols [0,64) per chunk)
  float* beta          = (float*)alloc((size_t)ROWS * NHh * 4);           // 0.5MB
  // After conv, qkvh dead: WY buffers alias it (3 x 32MB = 96MB exact)
  unsigned short* Wch = qkvh;                              // [2048][64][128]
  unsigned short* Uch = qkvh + (size_t)2048 * 8192;        // [2048][64][128]
  unsigned short* Kth = qkvh + (size_t)2 * 2048 * 8192;    // [2048][128][64]
  unsigned short* obb = qkvh;  // rmsn out, after recB (W region dead)

  cast_x_k<<<ROWS * Hm / 1024, 256, 0, stream>>>(x, xb);
  cast_w_k<<<Hm * Hm / 256, 256, 0, stream>>>(Wq, Wk, Wv, Wo, wqkv, wob);
  gemm256<true><<<dim3(QKVN / 256, ROWS / 256), 512, 0, stream>>>(xb, wqkv, qkvh, ROWS, QKVN, Hm);
  beta_k<<<ROWS / 4, 256, 0, stream>>>(x, Wb, beta);
  conv_k<<<dim3(Hm / 256, Ss / 32, Bb * 3), 256, 0, stream>>>(qkvh, cq, ck, cv, qb, kb, vb);
  recA_k<<<dim3(NC, 32), 256, 0, stream>>>(qb, kb, vb, beta, Wch, Uch, Kth);
  recB_k<<<dim3(8, 32), 256, 0, stream>>>(qb, kb, Wch, Uch, Kth, o_b);
  rmsn_k<<<ROWS, 256, 0, stream>>>(o_b, rw, obb);
  gemm256<false><<<dim3(Hm / 256, ROWS / 256), 512, 0, stream>>>(obb, wob, out, ROWS, Hm, Hm);
}

// Round 4
// 920.342 us; speedup vs baseline: 1.3374x; 1.0474x over previous
//
#include <hip/hip_runtime.h>

#define DI __device__ __forceinline__

constexpr int Bb = 2, Ss = 4096, Hm = 2048, NHh = 16, HDd = 128;
constexpr int ROWS = Bb * Ss;   // 8192
constexpr int QKVN = 3 * Hm;    // 6144
constexpr int CC = 64;          // chunk length
constexpr int NC = Ss / CC;     // 64 chunks per (b,h)

typedef __bf16 bf16x8 __attribute__((ext_vector_type(8)));
typedef float f32x4 __attribute__((ext_vector_type(4)));

DI unsigned short f2bf(float f) {
  unsigned int u = __float_as_uint(f);
  u = u + 0x7FFFu + ((u >> 16) & 1u);   // round-to-nearest-even
  return (unsigned short)(u >> 16);
}
DI float bf2f(unsigned int u) { return __uint_as_float(u << 16); }
DI void ld_bf8(const unsigned short* p, float* f) {
  uint4 u = *(const uint4*)p;
  f[0] = bf2f(u.x & 0xffffu); f[1] = bf2f(u.x >> 16);
  f[2] = bf2f(u.y & 0xffffu); f[3] = bf2f(u.y >> 16);
  f[4] = bf2f(u.z & 0xffffu); f[5] = bf2f(u.z >> 16);
  f[6] = bf2f(u.w & 0xffffu); f[7] = bf2f(u.w >> 16);
}

// async global->LDS, 16B/lane, lds dest = base + lane*16 (wave-uniform base)
DI void gld16(const unsigned short* g, unsigned short* l) {
  __builtin_amdgcn_global_load_lds(
      (const __attribute__((address_space(1))) unsigned int*)g,
      (__attribute__((address_space(3))) unsigned int*)l, 16, 0, 0);
}

// raw barrier with LDS-only drain: does NOT wait vmcnt (global loads/stores
// stay in flight across the barrier — T4 counted-vmcnt discipline).
DI void bar_lds() {
  asm volatile("s_waitcnt lgkmcnt(0)" ::: "memory");
  __builtin_amdgcn_s_barrier();
}

// ---------------- cast x -> bf16 ----------------
__global__ void cast_x_k(const float* __restrict__ x, unsigned short* __restrict__ xb) {
  int i = blockIdx.x * 256 + threadIdx.x;
  float4 f = ((const float4*)x)[i];
  ushort4 u;
  u.x = f2bf(f.x); u.y = f2bf(f.y); u.z = f2bf(f.z); u.w = f2bf(f.w);
  ((ushort4*)xb)[i] = u;
}

// ---------------- cast weights -> bf16 (Wq|Wk|Wv concat, Wo) ----------------
__global__ void cast_w_k(const float* __restrict__ Wq, const float* __restrict__ Wk,
                         const float* __restrict__ Wv, const float* __restrict__ Wo,
                         unsigned short* __restrict__ wqkv, unsigned short* __restrict__ wo) {
  const int W1 = Hm * Hm;
  int idx = blockIdx.x * 256 + threadIdx.x;
  for (int r = 0; r < 4; r++) {
    int i = idx + r * W1;
    if (i < W1)            wqkv[i] = f2bf(Wq[i]);
    else if (i < 2 * W1)   wqkv[i] = f2bf(Wk[i - W1]);
    else if (i < 3 * W1)   wqkv[i] = f2bf(Wv[i - 2 * W1]);
    else                   wo[i - 3 * W1] = f2bf(Wo[i - 3 * W1]);
  }
}

// ---------------- 256x256 8-phase bf16 NT GEMM (T1+T2+T3+T4+T5) ----------------
// 512 thr = 8 waves (2M x 4N); BK=64; LDS 160KiB: A triple-buffered (3x32KB),
// B double-buffered (2x32KB). Deep pipeline: BOTH A(t+2) and B(t+2) staged
// during tile t (flight >= 5 phases before their gate), single vmcnt(8) gate
// per K-tile (8 loads/wave issued per tile; <=8 outstanding proves tile t+1
// fully landed). T2 swizzle via inverse-swizzled global source + swizzled
// ds_read (linear LDS dest for global_load_lds).
DI bf16x8 ldsw(const unsigned short* base, int r, int c16) {
  return *(const bf16x8*)&base[r * 64 + ((c16 ^ (r & 7)) << 3)];
}

template <bool BF16_OUT>
__global__ __launch_bounds__(512) void gemm256(const unsigned short* __restrict__ A,
                                               const unsigned short* __restrict__ Bm,
                                               void* __restrict__ Cout,
                                               int M, int N, int Kd) {
  __shared__ __align__(16) unsigned short As[3][16384];
  __shared__ __align__(16) unsigned short Bs[2][16384];
  int tid = threadIdx.x;
  int wave = tid >> 6, lane = tid & 63;
  int lm = lane & 15, lq = lane >> 4;
  int wm = (wave >> 2) * 128, wn = (wave & 3) * 64;

  // T1: bijective XCD swizzle (nwg % 8 == 0 for both call sites)
  int nx = N >> 8;
  int nwg = gridDim.x * gridDim.y;
  int lin = blockIdx.x + gridDim.x * blockIdx.y;
  int cpx = nwg >> 3;
  int swz = (lin & 7) * cpx + (lin >> 3);
  int bn = (swz % nx) << 8, bm = (swz / nx) << 8;

  int NT = Kd >> 6;
  // staging constants: lane covers phys 16B slot (l&7) of row-block offset (l>>3);
  // inverse swizzle: source col16 = (l&7) ^ (l>>3)
  int rsub = lane >> 3;
  int csw = ((lane & 7) ^ rsub) << 3;   // in shorts

  auto stageA = [&](int buf, int half, int ts) {
    int ksrc = (ts < NT ? ts : NT - 1) << 6;
#pragma unroll
    for (int i = 0; i < 2; i++) {
      int blk = wave * 2 + i;
      int r = half * 128 + blk * 8 + rsub;
      gld16(&A[(size_t)(bm + r) * Kd + ksrc + csw], &As[buf][half * 8192 + blk * 512]);
    }
  };
  auto stageB = [&](int buf, int half, int ts) {
    int ksrc = (ts < NT ? ts : NT - 1) << 6;
#pragma unroll
    for (int i = 0; i < 2; i++) {
      int blk = wave * 2 + i;
      int r = half * 128 + blk * 8 + rsub;
      gld16(&Bm[(size_t)(bn + r) * Kd + ksrc + csw], &Bs[buf][half * 8192 + blk * 512]);
    }
  };

  f32x4 acc[8][4] = {};
  bf16x8 a[4][2], b[4][2];

  // prologue: tiles 0 and 1 fully staged; wait tile0 (8 loads of tile1 in flight)
  stageA(0, 0, 0); stageA(0, 1, 0); stageB(0, 0, 0); stageB(0, 1, 0);
  stageA(1, 0, 1); stageA(1, 1, 1); stageB(1, 0, 1); stageB(1, 1, 1);
  asm volatile("s_waitcnt vmcnt(8)" ::: "memory");
  __builtin_amdgcn_s_barrier();

  int cur_a = 0, cur_b = 0;
  for (int t = 0; t < NT; t++) {
    const unsigned short* Ac = As[cur_a];
    const unsigned short* Bc = Bs[cur_b];
    int ap2 = cur_a == 0 ? 2 : cur_a - 1;   // (t+2)%3 == (t-1)%3

    // ---- ph0: read A lo (fi0-3) + B lo (fj0-1); stage A0(t+2); MFMA Q(lo,lo)
#pragma unroll
    for (int fi = 0; fi < 4; fi++)
#pragma unroll
      for (int kk = 0; kk < 2; kk++)
        a[fi][kk] = ldsw(Ac, wm + fi * 16 + lm, kk * 4 + lq);
#pragma unroll
    for (int fj = 0; fj < 2; fj++)
#pragma unroll
      for (int kk = 0; kk < 2; kk++)
        b[fj][kk] = ldsw(Bc, wn + fj * 16 + lm, kk * 4 + lq);
    stageA(ap2, 0, t + 2);
    asm volatile("" ::: "memory");
    __builtin_amdgcn_s_barrier();
    asm volatile("s_waitcnt lgkmcnt(0)" ::: "memory");
    __builtin_amdgcn_sched_barrier(0);
    __builtin_amdgcn_s_setprio(1);
#pragma unroll
    for (int kk = 0; kk < 2; kk++)
#pragma unroll
      for (int fi = 0; fi < 4; fi++)
#pragma unroll
        for (int fj = 0; fj < 2; fj++)
          acc[fi][fj] = __builtin_amdgcn_mfma_f32_16x16x32_bf16(a[fi][kk], b[fj][kk], acc[fi][fj], 0, 0, 0);
    __builtin_amdgcn_s_setprio(0);
    asm volatile("" ::: "memory");
    __builtin_amdgcn_s_barrier();

    // ---- ph1: read B hi (fj2-3); stage A1(t+2); MFMA Q(lo,hi)
#pragma unroll
    for (int fj = 0; fj < 2; fj++)
#pragma unroll
      for (int kk = 0; kk < 2; kk++)
        b[2 + fj][kk] = ldsw(Bc, wn + (2 + fj) * 16 + lm, kk * 4 + lq);
    stageA(ap2, 1, t + 2);
    asm volatile("" ::: "memory");
    __builtin_amdgcn_s_barrier();
    asm volatile("s_waitcnt lgkmcnt(0)" ::: "memory");
    __builtin_amdgcn_sched_barrier(0);
    __builtin_amdgcn_s_setprio(1);
#pragma unroll
    for (int kk = 0; kk < 2; kk++)
#pragma unroll
      for (int fi = 0; fi < 4; fi++)
#pragma unroll
        for (int fj = 0; fj < 2; fj++)
          acc[fi][2 + fj] = __builtin_amdgcn_mfma_f32_16x16x32_bf16(a[fi][kk], b[2 + fj][kk], acc[fi][2 + fj], 0, 0, 0);
    __builtin_amdgcn_s_setprio(0);
    asm volatile("" ::: "memory");
    __builtin_amdgcn_s_barrier();

    // ---- ph2: read A hi (fi4-7, reuse a[]); stage B0(t+2)->cur_b (lo died ph0); MFMA Q(hi,hi)
#pragma unroll
    for (int fi = 0; fi < 4; fi++)
#pragma unroll
      for (int kk = 0; kk < 2; kk++)
        a[fi][kk] = ldsw(Ac, wm + 64 + fi * 16 + lm, kk * 4 + lq);
    stageB(cur_b, 0, t + 2);
    asm volatile("" ::: "memory");
    __builtin_amdgcn_s_barrier();
    asm volatile("s_waitcnt lgkmcnt(0)" ::: "memory");
    __builtin_amdgcn_sched_barrier(0);
    __builtin_amdgcn_s_setprio(1);
#pragma unroll
    for (int kk = 0; kk < 2; kk++)
#pragma unroll
      for (int fi = 0; fi < 4; fi++)
#pragma unroll
        for (int fj = 0; fj < 2; fj++)
          acc[4 + fi][2 + fj] = __builtin_amdgcn_mfma_f32_16x16x32_bf16(a[fi][kk], b[2 + fj][kk], acc[4 + fi][2 + fj], 0, 0, 0);
    __builtin_amdgcn_s_setprio(0);
    asm volatile("" ::: "memory");
    __builtin_amdgcn_s_barrier();

    // ---- ph3: no ds_reads; stage B1(t+2) (hi died ph1); MFMA Q(hi,lo); vmcnt(8) gates tile t+1
    stageB(cur_b, 1, t + 2);
    asm volatile("" ::: "memory");
    __builtin_amdgcn_s_barrier();
    __builtin_amdgcn_s_setprio(1);
#pragma unroll
    for (int kk = 0; kk < 2; kk++)
#pragma unroll
      for (int fi = 0; fi < 4; fi++)
#pragma unroll
        for (int fj = 0; fj < 2; fj++)
          acc[4 + fi][fj] = __builtin_amdgcn_mfma_f32_16x16x32_bf16(a[fi][kk], b[fj][kk], acc[4 + fi][fj], 0, 0, 0);
    __builtin_amdgcn_s_setprio(0);
    asm volatile("s_waitcnt vmcnt(8)" ::: "memory");
    __builtin_amdgcn_s_barrier();

    cur_a = cur_a == 2 ? 0 : cur_a + 1;
    cur_b ^= 1;
  }

  // epilogue
#pragma unroll
  for (int fi = 0; fi < 8; fi++)
#pragma unroll
    for (int fj = 0; fj < 4; fj++) {
      int row = bm + wm + fi * 16 + lq * 4;
      int col = bn + wn + fj * 16 + lm;
#pragma unroll
      for (int r = 0; r < 4; r++) {
        if (BF16_OUT)
          ((unsigned short*)Cout)[(size_t)(row + r) * N + col] = f2bf(acc[fi][fj][r]);
        else
          ((float*)Cout)[(size_t)(row + r) * N + col] = acc[fi][fj][r];
      }
    }
}

// ---------------- causal conv K=4 + silu + (l2norm for q/k), bf16 in/out ----------------
__global__ __launch_bounds__(256) void conv_k(const unsigned short* __restrict__ qkvh,
                                              const float* __restrict__ cwq,
                                              const float* __restrict__ cwk,
                                              const float* __restrict__ cwv,
                                              unsigned short* __restrict__ qb,
                                              unsigned short* __restrict__ kb,
                                              unsigned short* __restrict__ vb) {
  __shared__ __align__(16) float sm[32 * 260];   // pad 260: bank stride 4, not 0
  __shared__ float fac[64];
  int tid = threadIdx.x;
  int cblk = blockIdx.x * 256;
  int s0 = blockIdx.y * 32;
  int z = blockIdx.z;
  int sel = z >> 1, b = z & 1;
  const float* cw = sel == 0 ? cwq : (sel == 1 ? cwk : cwv);
  int c = cblk + tid;
  float4 w = ((const float4*)cw)[c];
  const unsigned short* in = qkvh + (size_t)b * Ss * QKVN + sel * Hm + c;
  float x0 = (s0 >= 3) ? bf2f(in[(size_t)(s0 - 3) * QKVN]) : 0.f;
  float x1 = (s0 >= 2) ? bf2f(in[(size_t)(s0 - 2) * QKVN]) : 0.f;
  float x2 = (s0 >= 1) ? bf2f(in[(size_t)(s0 - 1) * QKVN]) : 0.f;
  for (int si = 0; si < 32; si++) {
    float x3 = bf2f(in[(size_t)(s0 + si) * QKVN]);
    float a = w.x * x0 + w.y * x1 + w.z * x2 + w.w * x3;
    sm[si * 260 + tid] = a / (1.f + __expf(-a));
    x0 = x1; x1 = x2; x2 = x3;
  }
  __syncthreads();
  if (sel < 2) {
    int si = tid >> 3, p = tid & 7;
    const float* row = &sm[si * 260 + p * 32];
    float ss = 0.f;
#pragma unroll
    for (int j = 0; j < 32; j += 4) {
      float4 v4 = *(const float4*)(row + j);
      ss += v4.x * v4.x + v4.y * v4.y + v4.z * v4.z + v4.w * v4.w;
    }
    ss += __shfl_xor(ss, 1);
    ss += __shfl_xor(ss, 2);
    float f = rsqrtf(ss + 1e-6f);
    if (sel == 0) f *= 0.08838834764831845f;
    if ((p & 3) == 0) fac[si * 2 + (p >> 2)] = f;
  }
  __syncthreads();
  unsigned short* outp = sel == 0 ? qb : (sel == 1 ? kb : vb);
  int hl = tid >> 7;
  for (int si = 0; si < 32; si++) {
    float val = sm[si * 260 + tid];
    if (sel < 2) val *= fac[si * 2 + hl];
    outp[(size_t)(b * Ss + s0 + si) * Hm + cblk + tid] = f2bf(val);
  }
}

// ---------------- beta = sigmoid(x @ Wb^T), fp32 ----------------
__global__ __launch_bounds__(256) void beta_k(const float* __restrict__ x,
                                              const float* __restrict__ Wbm,
                                              float* __restrict__ beta) {
  int wid = threadIdx.x >> 6, lane = threadIdx.x & 63;
  int row = blockIdx.x * 4 + wid;
  int h = lane & 15, part = lane >> 4;
  const float* xr = x + (size_t)row * Hm + part * 512;
  const float* wr = Wbm + (size_t)h * Hm + part * 512;
  float acc = 0.f;
  for (int j = 0; j < 512; j += 4) {
    float4 xv = *(const float4*)(xr + j);
    float4 wv = *(const float4*)(wr + j);
    acc += xv.x * wv.x + xv.y * wv.y + xv.z * wv.z + xv.w * wv.w;
  }
  acc += __shfl_xor(acc, 16);
  acc += __shfl_xor(acc, 32);
  if (part == 0) beta[(size_t)row * NHh + h] = 1.f / (1.f + __expf(-acc));
}

// ---------------- recA: per-chunk WY precompute + At, doubling-based inverse ----------------
// grid (NC, 32). Outputs: W[cid][t][d], U[cid][t][v], Kt[cid][d][s]; At into kg's own chunk cols [0,64)
__global__ __launch_bounds__(256) void recA_k(const unsigned short* __restrict__ qg,
                                              unsigned short* kg,   // read K, write At
                                              const unsigned short* __restrict__ vg,
                                              const float* __restrict__ beta,
                                              unsigned short* __restrict__ Wo_,
                                              unsigned short* __restrict__ Uo,
                                              unsigned short* __restrict__ Kto) {
  __shared__ __align__(16) unsigned short Kc[64 * 136];
  __shared__ __align__(16) unsigned short Qc[64 * 136];
  __shared__ __align__(16) unsigned short Vt[128 * 72];
  __shared__ __align__(16) unsigned short Kt[128 * 72];
  __shared__ __align__(16) unsigned short Xa[64 * 72], Xat[64 * 72];
  __shared__ __align__(16) unsigned short Xb2[64 * 72], Xbt[64 * 72];
  __shared__ __align__(16) unsigned short Pa[64 * 72], Pb[64 * 72];
  __shared__ float bl[64];
  int tid = threadIdx.x;
  int c = blockIdx.x, bh = blockIdx.y;
  int b = bh >> 4, h = bh & 15;
  size_t cid = (size_t)bh * NC + c;
  size_t rowbase = (size_t)b * Ss + (size_t)c * CC;
  int wave = tid >> 6, lane = tid & 63, lm = lane & 15, lq = lane >> 4;

  // stage K, Q chunks (16B), V transposed (scalar), beta
  for (int idx = tid; idx < 1024; idx += 256) {
    int r = idx >> 4, c8 = (idx & 15) * 8;
    *(uint4*)&Kc[r * 136 + c8] = *(const uint4*)&kg[(rowbase + r) * Hm + h * HDd + c8];
    *(uint4*)&Qc[r * 136 + c8] = *(const uint4*)&qg[(rowbase + r) * Hm + h * HDd + c8];
  }
  for (int idx = tid; idx < 8192; idx += 256) {
    int s = idx >> 7, vv = idx & 127;
    Vt[vv * 72 + s] = vg[(rowbase + s) * Hm + h * HDd + vv];
  }
  if (tid < 64) bl[tid] = beta[(rowbase + tid) * NHh + h];
  __syncthreads();

  // Kt = K^T (LDS transpose)
  for (int idx = tid; idx < 8192; idx += 256) {
    int s = idx >> 7, d = idx & 127;
    Kt[d * 72 + s] = Kc[s * 136 + d];
  }
  // accA = K K^T -> M = -strict_tril(diag(beta) K K^T); write M, M^T, P0 = I + M
  {
    f32x4 accA[4] = {};
#pragma unroll
    for (int kk = 0; kk < 4; kk++) {
      bf16x8 af = *(const bf16x8*)&Kc[(wave * 16 + lm) * 136 + kk * 32 + lq * 8];
#pragma unroll
      for (int st = 0; st < 4; st++) {
        bf16x8 bfr = *(const bf16x8*)&Kc[(st * 16 + lm) * 136 + kk * 32 + lq * 8];
        accA[st] = __builtin_amdgcn_mfma_f32_16x16x32_bf16(af, bfr, accA[st], 0, 0, 0);
      }
    }
#pragma unroll
    for (int st = 0; st < 4; st++)
#pragma unroll
      for (int r = 0; r < 4; r++) {
        int t = wave * 16 + lq * 4 + r, s = st * 16 + lm;
        float m = (t > s) ? -bl[t] * accA[st][r] : 0.f;
        unsigned short mb = f2bf(m);
        Xa[t * 72 + s] = mb;
        Xat[s * 72 + t] = mb;
        Pa[t * 72 + s] = (t == s) ? f2bf(1.f) : mb;
      }
  }
  // At = mask(Q K^T) written into kg's own chunk region cols [0,64)
  {
    f32x4 accQ[4] = {};
#pragma unroll
    for (int kk = 0; kk < 4; kk++) {
      bf16x8 af = *(const bf16x8*)&Qc[(wave * 16 + lm) * 136 + kk * 32 + lq * 8];
#pragma unroll
      for (int st = 0; st < 4; st++) {
        bf16x8 bfr = *(const bf16x8*)&Kc[(st * 16 + lm) * 136 + kk * 32 + lq * 8];
        accQ[st] = __builtin_amdgcn_mfma_f32_16x16x32_bf16(af, bfr, accQ[st], 0, 0, 0);
      }
    }
#pragma unroll
    for (int st = 0; st < 4; st++)
#pragma unroll
      for (int r = 0; r < 4; r++) {
        int t = wave * 16 + lq * 4 + r, s = st * 16 + lm;
        kg[(rowbase + t) * Hm + h * HDd + s] = (s <= t) ? f2bf(accQ[st][r]) : (unsigned short)0;
      }
  }
  __syncthreads();

  // doubling: T = (I-M)^-1 = prod_{k=0..5} (I + M^(2^k)); carry (X, X^T) pairs
  unsigned short *X = Xa, *Xt = Xat, *Xn = Xb2, *Xnt = Xbt, *P = Pa, *Pn = Pb;
  for (int lvl = 1; lvl <= 5; lvl++) {
    // Xn = NT(X, Xt) = X*X ; Xnt = NT(Xt, X) = (X*X)^T
    f32x4 a1[4] = {}, a2[4] = {};
#pragma unroll
    for (int kk = 0; kk < 2; kk++) {
      bf16x8 afx  = *(const bf16x8*)&X[(wave * 16 + lm) * 72 + kk * 32 + lq * 8];
      bf16x8 afxt = *(const bf16x8*)&Xt[(wave * 16 + lm) * 72 + kk * 32 + lq * 8];
#pragma unroll
      for (int st = 0; st < 4; st++) {
        bf16x8 bx  = *(const bf16x8*)&X[(st * 16 + lm) * 72 + kk * 32 + lq * 8];
        bf16x8 bxt = *(const bf16x8*)&Xt[(st * 16 + lm) * 72 + kk * 32 + lq * 8];
        a1[st] = __builtin_amdgcn_mfma_f32_16x16x32_bf16(afx, bxt, a1[st], 0, 0, 0);
        a2[st] = __builtin_amdgcn_mfma_f32_16x16x32_bf16(afxt, bx, a2[st], 0, 0, 0);
      }
    }
#pragma unroll
    for (int st = 0; st < 4; st++)
#pragma unroll
      for (int r = 0; r < 4; r++) {
        int t = wave * 16 + lq * 4 + r, s = st * 16 + lm;
        Xn[t * 72 + s]  = f2bf(a1[st][r]);
        Xnt[t * 72 + s] = f2bf(a2[st][r]);
      }
    __syncthreads();
    // Pn = P + P*Xn = NT(P, Xnt) with acc seeded by P
    f32x4 ap[4];
#pragma unroll
    for (int st = 0; st < 4; st++)
#pragma unroll
      for (int r = 0; r < 4; r++)
        ap[st][r] = bf2f(P[(wave * 16 + lq * 4 + r) * 72 + st * 16 + lm]);
#pragma unroll
    for (int kk = 0; kk < 2; kk++) {
      bf16x8 afp = *(const bf16x8*)&P[(wave * 16 + lm) * 72 + kk * 32 + lq * 8];
#pragma unroll
      for (int st = 0; st < 4; st++) {
        bf16x8 bxnt = *(const bf16x8*)&Xnt[(st * 16 + lm) * 72 + kk * 32 + lq * 8];
        ap[st] = __builtin_amdgcn_mfma_f32_16x16x32_bf16(afp, bxnt, ap[st], 0, 0, 0);
      }
    }
#pragma unroll
    for (int st = 0; st < 4; st++)
#pragma unroll
      for (int r = 0; r < 4; r++) {
        int t = wave * 16 + lq * 4 + r, s = st * 16 + lm;
        // last level: fold in diag(beta) -> Tb
        Pn[t * 72 + s] = f2bf((lvl == 5) ? ap[st][r] * bl[s] : ap[st][r]);
      }
    // swap
    unsigned short* tmp;
    tmp = X; X = Xn; Xn = tmp;
    tmp = Xt; Xt = Xnt; Xnt = tmp;
    tmp = P; P = Pn; Pn = tmp;
    __syncthreads();
  }

  // store Kt to global
  for (int idx = tid; idx < 1024; idx += 256) {
    int d = idx >> 3, s8 = (idx & 7) * 8;
    *(uint4*)&Kto[cid * 8192 + d * 64 + s8] = *(const uint4*)&Kt[d * 72 + s8];
  }
  // U = NT(Tb, Vt) ; W = NT(Tb, Kt)   (Tb = P)
  {
    unsigned short* Up = Uo + cid * 8192;
    unsigned short* Wp = Wo_ + cid * 8192;
    f32x4 accU[8] = {}, accW[8] = {};
#pragma unroll
    for (int kk = 0; kk < 2; kk++) {
      bf16x8 af = *(const bf16x8*)&P[(wave * 16 + lm) * 72 + kk * 32 + lq * 8];
#pragma unroll
      for (int nt = 0; nt < 8; nt++) {
        bf16x8 bv = *(const bf16x8*)&Vt[(nt * 16 + lm) * 72 + kk * 32 + lq * 8];
        bf16x8 bk = *(const bf16x8*)&Kt[(nt * 16 + lm) * 72 + kk * 32 + lq * 8];
        accU[nt] = __builtin_amdgcn_mfma_f32_16x16x32_bf16(af, bv, accU[nt], 0, 0, 0);
        accW[nt] = __builtin_amdgcn_mfma_f32_16x16x32_bf16(af, bk, accW[nt], 0, 0, 0);
      }
    }
#pragma unroll
    for (int nt = 0; nt < 8; nt++)
#pragma unroll
      for (int r = 0; r < 4; r++) {
        int t = wave * 16 + lq * 4 + r, n = nt * 16 + lm;
        Up[t * 128 + n] = f2bf(accU[nt][r]);
        Wp[t * 128 + n] = f2bf(accW[nt][r]);
      }
  }
}

// ---------------- recB: sequential chunk scan, 256 WGs (8 v-slices x 32 bh) ----------------
__global__ __launch_bounds__(256) void recB_k(const unsigned short* __restrict__ qg,
                                              const unsigned short* __restrict__ atg,
                                              const unsigned short* __restrict__ Wg,
                                              const unsigned short* __restrict__ Ug,
                                              const unsigned short* __restrict__ Ktg,
                                              unsigned short* __restrict__ og) {
  __shared__ __align__(16) unsigned short Wc[64 * 136];
  __shared__ __align__(16) unsigned short Qc[64 * 136];
  __shared__ __align__(16) unsigned short Ktc[128 * 72];
  __shared__ __align__(16) unsigned short Atc[64 * 72];
  __shared__ __align__(16) unsigned short Uc[64 * 24];
  __shared__ __align__(16) unsigned short Dt[16 * 72];
  __shared__ __align__(16) unsigned short Stb[16 * 136];
  __shared__ float St32[16 * 132];
  int tid = threadIdx.x;
  // XCD-aware swizzle: all 8 v-slices of one (b,h) on the same XCD (id%8).
  int lin = blockIdx.x + (blockIdx.y << 3);
  int xcd = lin & 7, slot = lin >> 3;
  int vs = slot & 7;
  int bh = xcd + ((slot >> 3) << 3);
  int b = bh >> 4, h = bh & 15, v0 = vs * 16;
  int wave = tid >> 6, lane = tid & 63, lm = lane & 15, lq = lane >> 4;

  for (int i = tid; i < 16 * 132; i += 256) St32[i] = 0.f;
  for (int i = tid; i < 16 * 136; i += 256) Stb[i] = 0;

  // prologue: stage chunk 0 directly
  {
    size_t cid0 = (size_t)bh * NC;
    size_t rb0 = (size_t)b * Ss;
    const unsigned short* Wp = Wg + cid0 * 8192;
    const unsigned short* Ktp = Ktg + cid0 * 8192;
    const unsigned short* Up = Ug + cid0 * 8192 + v0;
#pragma unroll
    for (int j = 0; j < 4; j++) {
      int idx = tid + j * 256;
      int r = idx >> 4, c8 = (idx & 15) * 8;
      *(uint4*)&Wc[r * 136 + c8] = *(const uint4*)&Wp[r * 128 + c8];
      *(uint4*)&Qc[r * 136 + c8] = *(const uint4*)&qg[(rb0 + r) * Hm + h * HDd + c8];
      int r2 = idx >> 3, d8 = (idx & 7) * 8;
      *(uint4*)&Ktc[r2 * 72 + d8] = *(const uint4*)&Ktp[r2 * 64 + d8];
    }
#pragma unroll
    for (int j = 0; j < 2; j++) {
      int idx = tid + j * 256;
      int t = idx >> 3, s8 = (idx & 7) * 8;
      *(uint4*)&Atc[t * 72 + s8] = *(const uint4*)&atg[(rb0 + t) * Hm + h * HDd + s8];
    }
    if (tid < 128) {
      int t = tid >> 1, c8 = (tid & 1) * 8;
      *(uint4*)&Uc[t * 24 + c8] = *(const uint4*)&Up[t * 128 + c8];
    }
  }
  __syncthreads();

  for (int c = 0; c < NC; c++) {
    size_t rb = (size_t)b * Ss + (size_t)c * CC;
    // issue prefetch of chunk c+1 into registers (consumed in write-slot).
    // With bar_lds() these loads stay in flight across BOTH phase barriers;
    // the only wait is the compiler's counted vmcnt at first register use.
    int cn = (c + 1 < NC) ? c + 1 : c;
    size_t cidn = (size_t)bh * NC + cn;
    size_t rbn = (size_t)b * Ss + (size_t)cn * CC;
    const unsigned short* Wpn = Wg + cidn * 8192;
    const unsigned short* Ktpn = Ktg + cidn * 8192;
    const unsigned short* Upn = Ug + cidn * 8192 + v0;
    uint4 pw[4], pq[4], pk[4], pa[2], pu;
#pragma unroll
    for (int j = 0; j < 4; j++) {
      int idx = tid + j * 256;
      int r = idx >> 4, c8 = (idx & 15) * 8;
      pw[j] = *(const uint4*)&Wpn[r * 128 + c8];
      pq[j] = *(const uint4*)&qg[(rbn + r) * Hm + h * HDd + c8];
      int r2 = idx >> 3, d8 = (idx & 7) * 8;
      pk[j] = *(const uint4*)&Ktpn[r2 * 64 + d8];
    }
#pragma unroll
    for (int j = 0; j < 2; j++) {
      int idx = tid + j * 256;
      int t = idx >> 3, s8 = (idx & 7) * 8;
      pa[j] = *(const uint4*)&atg[(rbn + t) * Hm + h * HDd + s8];
    }
    if (tid < 128) {
      int t = tid >> 1, c8 = (tid & 1) * 8;
      pu = *(const uint4*)&Upn[t * 128 + c8];
    }

    // phase2: accD = NT(Wc, Stb) [64t x 16v]; Dt[v][t] = U - accD
    {
      f32x4 accD = {};
#pragma unroll
      for (int kk = 0; kk < 4; kk++) {
        bf16x8 af = *(const bf16x8*)&Wc[(wave * 16 + lm) * 136 + kk * 32 + lq * 8];
        bf16x8 bfr = *(const bf16x8*)&Stb[lm * 136 + kk * 32 + lq * 8];
        accD = __builtin_amdgcn_mfma_f32_16x16x32_bf16(af, bfr, accD, 0, 0, 0);
      }
#pragma unroll
      for (int r = 0; r < 4; r++) {
        int t = wave * 16 + lq * 4 + r;
        float dv = bf2f(Uc[t * 24 + lm]) - accD[r];
        Dt[lm * 72 + t] = f2bf(dv);
      }
    }
    bar_lds();   // A: Dt visible; prefetch loads remain in flight

    // phase3+4 fused: accO = NT(Qc,Stb) + NT(Atc,Dt); accP = NT(Dt,Ktc)
    f32x4 accO = {};
    f32x4 accP[2] = {};
    {
#pragma unroll
      for (int kk = 0; kk < 4; kk++) {
        bf16x8 af = *(const bf16x8*)&Qc[(wave * 16 + lm) * 136 + kk * 32 + lq * 8];
        bf16x8 bfr = *(const bf16x8*)&Stb[lm * 136 + kk * 32 + lq * 8];
        accO = __builtin_amdgcn_mfma_f32_16x16x32_bf16(af, bfr, accO, 0, 0, 0);
      }
#pragma unroll
      for (int kk = 0; kk < 2; kk++) {
        bf16x8 af = *(const bf16x8*)&Atc[(wave * 16 + lm) * 72 + kk * 32 + lq * 8];
        bf16x8 bfr = *(const bf16x8*)&Dt[lm * 72 + kk * 32 + lq * 8];
        accO = __builtin_amdgcn_mfma_f32_16x16x32_bf16(af, bfr, accO, 0, 0, 0);
        bf16x8 afd = *(const bf16x8*)&Dt[lm * 72 + kk * 32 + lq * 8];
#pragma unroll
        for (int j = 0; j < 2; j++) {
          int dt = wave * 2 + j;
          bf16x8 bk = *(const bf16x8*)&Ktc[(dt * 16 + lm) * 72 + kk * 32 + lq * 8];
          accP[j] = __builtin_amdgcn_mfma_f32_16x16x32_bf16(afd, bk, accP[j], 0, 0, 0);
        }
      }
    }
    bar_lds();   // B: phase3 LDS reads complete; chunk buffers may be overwritten

    // write-slot: O -> global (fire-and-forget), state update, store prefetched chunk
#pragma unroll
    for (int r = 0; r < 4; r++) {
      int t = wave * 16 + lq * 4 + r;
      og[(rb + t) * Hm + h * HDd + v0 + lm] = f2bf(accO[r]);
    }
#pragma unroll
    for (int j = 0; j < 2; j++) {
      int dt = wave * 2 + j;
#pragma unroll
      for (int r = 0; r < 4; r++) {
        int vv = lq * 4 + r, d = dt * 16 + lm;
        float ns = St32[vv * 132 + d] + accP[j][r];
        St32[vv * 132 + d] = ns;
        Stb[vv * 136 + d] = f2bf(ns);
      }
    }
#pragma unroll
    for (int j = 0; j < 4; j++) {
      int idx = tid + j * 256;
      int r = idx >> 4, c8 = (idx & 15) * 8;
      *(uint4*)&Wc[r * 136 + c8] = pw[j];
      *(uint4*)&Qc[r * 136 + c8] = pq[j];
      int r2 = idx >> 3, d8 = (idx & 7) * 8;
      *(uint4*)&Ktc[r2 * 72 + d8] = pk[j];
    }
#pragma unroll
    for (int j = 0; j < 2; j++) {
      int idx = tid + j * 256;
      int t = idx >> 3, s8 = (idx & 7) * 8;
      *(uint4*)&Atc[t * 72 + s8] = pa[j];
    }
    if (tid < 128) {
      int t = tid >> 1, c8 = (tid & 1) * 8;
      *(uint4*)&Uc[t * 24 + c8] = pu;
    }
    bar_lds();   // C: new chunk + state visible; og stores NOT drained
  }
}

// ---------------- RMSNorm over head_dim + bf16 in/out ----------------
__global__ __launch_bounds__(256) void rmsn_k(const unsigned short* __restrict__ o,
                                              const float* __restrict__ rw,
                                              unsigned short* __restrict__ ob) {
  int tid = threadIdx.x;
  size_t rowoff = (size_t)blockIdx.x * Hm + tid * 8;
  float f[8];
  ld_bf8(o + rowoff, f);
  float ss = f[0]*f[0] + f[1]*f[1] + f[2]*f[2] + f[3]*f[3] +
             f[4]*f[4] + f[5]*f[5] + f[6]*f[6] + f[7]*f[7];
  ss += __shfl_xor(ss, 1); ss += __shfl_xor(ss, 2); ss += __shfl_xor(ss, 4); ss += __shfl_xor(ss, 8);
  float sc = rsqrtf(ss * (1.f / 128.f) + 1e-5f);
  int d = (tid & 15) * 8;
  float4 wa = *(const float4*)(rw + d);
  float4 wb = *(const float4*)(rw + d + 4);
  ushort4 u0, u1;
  u0.x = f2bf(f[0] * sc * wa.x); u0.y = f2bf(f[1] * sc * wa.y);
  u0.z = f2bf(f[2] * sc * wa.z); u0.w = f2bf(f[3] * sc * wa.w);
  u1.x = f2bf(f[4] * sc * wb.x); u1.y = f2bf(f[5] * sc * wb.y);
  u1.z = f2bf(f[6] * sc * wb.z); u1.w = f2bf(f[7] * sc * wb.w);
  ((ushort4*)ob)[rowoff / 4] = u0;
  ((ushort4*)ob)[rowoff / 4 + 1] = u1;
}

extern "C" void kernel_launch(void* const* d_in, const int* in_sizes, int n_in,
                              void* d_out, int out_size, void* d_ws, size_t ws_size,
                              hipStream_t stream) {
  const float* x  = (const float*)d_in[0];
  const float* Wq = (const float*)d_in[1];
  const float* Wk = (const float*)d_in[2];
  const float* Wv = (const float*)d_in[3];
  const float* Wb = (const float*)d_in[4];
  const float* Wo = (const float*)d_in[5];
  const float* cq = (const float*)d_in[6];
  const float* ck = (const float*)d_in[7];
  const float* cv = (const float*)d_in[8];
  const float* rw = (const float*)d_in[9];

  // d_out (64MB) as scratch: [0:32) xb then o; [32:64) vb. GEMM2 overwrites with fp32 out.
  unsigned short* xb  = (unsigned short*)d_out;
  unsigned short* vb  = (unsigned short*)d_out + (size_t)ROWS * Hm;
  unsigned short* o_b = (unsigned short*)d_out;
  float* out = (float*)d_out;

  // ws: 192.5 MB (proven footprint)
  char* ws = (char*)d_ws;
  size_t off = 0;
  auto alloc = [&](size_t bytes) {
    void* p = ws + off;
    off = (off + bytes + 255) & ~(size_t)255;
    return p;
  };
  unsigned short* wqkv = (unsigned short*)alloc((size_t)QKVN * Hm * 2);   // 24MB
  unsigned short* wob  = (unsigned short*)alloc((size_t)Hm * Hm * 2);     //  8MB
  unsigned short* qkvh = (unsigned short*)alloc((size_t)ROWS * QKVN * 2); // 96MB
  unsigned short* qb   = (unsigned short*)alloc((size_t)ROWS * Hm * 2);   // 32MB
  unsigned short* kb   = (unsigned short*)alloc((size_t)ROWS * Hm * 2);   // 32MB (K, then At in cols [0,64) per chunk)
  float* beta          = (float*)alloc((size_t)ROWS * NHh * 4);           // 0.5MB
  // After conv, qkvh dead: WY buffers alias it (3 x 32MB = 96MB exact)
  unsigned short* Wch = qkvh;                              // [2048][64][128]
  unsigned short* Uch = qkvh + (size_t)2048 * 8192;        // [2048][64][128]
  unsigned short* Kth = qkvh + (size_t)2 * 2048 * 8192;    // [2048][128][64]
  unsigned short* obb = qkvh;  // rmsn out, after recB (W region dead)

  cast_x_k<<<ROWS * Hm / 1024, 256, 0, stream>>>(x, xb);
  cast_w_k<<<Hm * Hm / 256, 256, 0, stream>>>(Wq, Wk, Wv, Wo, wqkv, wob);
  gemm256<true><<<dim3(QKVN / 256, ROWS / 256), 512, 0, stream>>>(xb, wqkv, qkvh, ROWS, QKVN, Hm);
  beta_k<<<ROWS / 4, 256, 0, stream>>>(x, Wb, beta);
  conv_k<<<dim3(Hm / 256, Ss / 32, Bb * 3), 256, 0, stream>>>(qkvh, cq, ck, cv, qb, kb, vb);
  recA_k<<<dim3(NC, 32), 256, 0, stream>>>(qb, kb, vb, beta, Wch, Uch, Kth);
  recB_k<<<dim3(8, 32), 256, 0, stream>>>(qb, kb, Wch, Uch, Kth, o_b);
  rmsn_k<<<ROWS, 256, 0, stream>>>(o_b, rw, obb);
  gemm256<false><<<dim3(Hm / 256, ROWS / 256), 512, 0, stream>>>(obb, wob, out, ROWS, Hm, Hm);
}